// Round 5
// baseline (549.360 us; speedup 1.0000x reference)
//
#include <hip/hip_runtime.h>
#include <hip/hip_bf16.h>

#define N_PTS 16384
#define DIMF  128
#define KNB   16
#define GRES  8
#define NCELL (GRES*GRES*GRES)

typedef __attribute__((ext_vector_type(8))) short bf16x8;
typedef __attribute__((ext_vector_type(4))) float f32x4;

__device__ __forceinline__ unsigned short f2b(float f){
  unsigned int u = __float_as_uint(f);
  u = u + 0x7fffu + ((u >> 16) & 1u);
  return (unsigned short)(u >> 16);
}

__device__ __forceinline__ float unsort_f(unsigned s){
  unsigned u = (s & 0x80000000u) ? (s ^ 0x80000000u) : ~s;
  return __uint_as_float(u);
}

// ---------------- KNN: grid build (GRES=8, 512 cells) ----------------
__global__ __launch_bounds__(256) void count_kernel(const float* __restrict__ pos, int* __restrict__ cnt){
  int i = blockIdx.x*256 + threadIdx.x;
  float px = pos[i*3+0], py = pos[i*3+1], pz = pos[i*3+2];
  int cx = min(GRES-1, max(0,(int)(px*(float)GRES)));
  int cy = min(GRES-1, max(0,(int)(py*(float)GRES)));
  int cz = min(GRES-1, max(0,(int)(pz*(float)GRES)));
  atomicAdd(&cnt[(cz*GRES+cy)*GRES+cx], 1);
}

__global__ __launch_bounds__(256) void scan_kernel(const int* __restrict__ cnt, int* __restrict__ starts, int* __restrict__ fillp){
  __shared__ int part[256];
  int t = threadIdx.x;
  int a = cnt[2*t], b = cnt[2*t+1];
  part[t] = a + b;
  __syncthreads();
  if (t == 0){
    int acc = 0;
    for (int i=0;i<256;++i){ int tmp = part[i]; part[i] = acc; acc += tmp; }
  }
  __syncthreads();
  int base = part[t];
  starts[2*t]   = base;     fillp[2*t]   = base;
  starts[2*t+1] = base + a; fillp[2*t+1] = base + a;
}

// sq stored numpy-style: ((x*x + y*y) + z*z), each op separately f32-rounded (no contraction)
__global__ __launch_bounds__(256) void scatter_kernel(const float* __restrict__ pos, int* __restrict__ fillp,
                                                      float4* __restrict__ pos4, int* __restrict__ pidx){
  int i = blockIdx.x*256 + threadIdx.x;
  float px = pos[i*3+0], py = pos[i*3+1], pz = pos[i*3+2];
  int cx = min(GRES-1, max(0,(int)(px*(float)GRES)));
  int cy = min(GRES-1, max(0,(int)(py*(float)GRES)));
  int cz = min(GRES-1, max(0,(int)(pz*(float)GRES)));
  int c = (cz*GRES+cy)*GRES+cx;
  float sq = __fadd_rn(__fadd_rn(__fmul_rn(px,px), __fmul_rn(py,py)), __fmul_rn(pz,pz));
  int s = atomicAdd(&fillp[c], 1);
  pos4[s] = make_float4(px, py, pz, sq);
  pidx[s] = i;
}

// Branchless 16-deep sorted insert of u64 key (ascending). INF inserts are no-ops.
#define INSERT16(U) { unsigned long long u_ = (U); \
  _Pragma("unroll") \
  for (int j_=0;j_<16;++j_){ \
    bool lt_ = u_ < kk[j_]; \
    unsigned long long a_ = lt_ ? u_ : kk[j_]; \
    u_ = lt_ ? kk[j_] : u_; \
    kk[j_] = a_; } }

// One wave (64 lanes) per point. Exact top-16 by (d2, idx) total order with d2
// replicating numpy float32 bit-exactly (same op sequence as the passing round).
// Keys: (sortable(d2)<<32)|idx, u64 ascending == lex (d2, idx) with XLA's
// -0.0 < +0.0 total order. Per-lane sorted-16 cap is unconditionally exact
// (a lane holds <=16 members of the global top-16). Merge: 16 rounds of
// wave-wide u64 min + winner shift. Geometric termination checked in f64 with
// 1e-5 slack; failures flagged for the exact serial fallback.
__global__ __launch_bounds__(256) void knn_query64(const float4* __restrict__ pos4, const int* __restrict__ pidx,
                                                   const int* __restrict__ starts, const int* __restrict__ cnt,
                                                   int* __restrict__ ind, char* __restrict__ flags){
  int lane = threadIdx.x & 63;
  int wv   = threadIdx.x >> 6;
  int t = blockIdx.x*4 + wv;
  float4 qp = pos4[t];
  int row = pidx[t];
  float qx = qp.x, qy = qp.y, qz = qp.z, qsq = qp.w;
  int cx = min(GRES-1, max(0,(int)(qx*(float)GRES)));
  int cy = min(GRES-1, max(0,(int)(qy*(float)GRES)));
  int cz = min(GRES-1, max(0,(int)(qz*(float)GRES)));

  unsigned long long kk[16];
  #pragma unroll
  for (int j=0;j<16;++j) kk[j] = ~0ull;

  int fill = 0;
  unsigned long long pend = ~0ull;

  // ---- rings 0+1: 3x3x3 box clipped to domain ----
  {
    int zlo = max(0,cz-1), zhi = min(GRES-1,cz+1);
    int ylo = max(0,cy-1), yhi = min(GRES-1,cy+1);
    int xlo = max(0,cx-1), xhi = min(GRES-1,cx+1);
    for (int zz=zlo; zz<=zhi; ++zz)
    for (int yy=ylo; yy<=yhi; ++yy)
    for (int xx=xlo; xx<=xhi; ++xx){
      int c = (zz*GRES+yy)*GRES+xx;
      int s0 = starts[c], n = cnt[c];
      while (n > 0){
        int take = min(n, 64 - fill);
        if (lane >= fill && lane < fill + take){
          int s = s0 + lane - fill;
          float4 pc = pos4[s];
          int idx = pidx[s];
          float dot = __fmaf_rn(qz, pc.z, __fmaf_rn(qy, pc.y, __fmul_rn(qx, pc.x)));
          float d   = __fsub_rn(__fadd_rn(qsq, pc.w), __fmul_rn(2.0f, dot));
          unsigned su = __float_as_uint(d);
          su ^= (unsigned)((int)su >> 31) | 0x80000000u;
          pend = ((unsigned long long)su << 32) | (unsigned)idx;
        }
        fill += take; s0 += take; n -= take;
        if (fill == 64){ INSERT16(pend); pend = ~0ull; fill = 0; }
      }
    }
  }
  INSERT16(pend); pend = ~0ull; fill = 0;   // flush partial window

  // ---- need ring 2? conservative bound: global16th <= wave-max of lane mins ----
  unsigned long long bup = kk[0];
  #pragma unroll
  for (int o=1;o<64;o<<=1){
    unsigned long long ot = __shfl_xor(bup, o, 64);
    bup = (ot > bup) ? ot : bup;
  }
  bool need2;
  if (bup == ~0ull) need2 = true;
  else {
    float b = unsort_f((unsigned)(bup >> 32));
    double mg = 1.0e300;
    double dqx=(double)qx, dqy=(double)qy, dqz=(double)qz;
    const double h = 0.125;
    if (cx-1 > 0)      mg = fmin(mg, dqx - (double)(cx-1)*h);
    if (cx+1 < GRES-1) mg = fmin(mg, (double)(cx+2)*h - dqx);
    if (cy-1 > 0)      mg = fmin(mg, dqy - (double)(cy-1)*h);
    if (cy+1 < GRES-1) mg = fmin(mg, (double)(cy+2)*h - dqy);
    if (cz-1 > 0)      mg = fmin(mg, dqz - (double)(cz-1)*h);
    if (cz+1 < GRES-1) mg = fmin(mg, (double)(cz+2)*h - dqz);
    need2 = !(mg*mg > (double)b + 1.0e-5);
  }

  if (need2){
    int zlo = max(0,cz-2), zhi = min(GRES-1,cz+2);
    int ylo = max(0,cy-2), yhi = min(GRES-1,cy+2);
    int xlo = max(0,cx-2), xhi = min(GRES-1,cx+2);
    for (int zz=zlo; zz<=zhi; ++zz)
    for (int yy=ylo; yy<=yhi; ++yy)
    for (int xx=xlo; xx<=xhi; ++xx){
      if (abs(zz-cz)<2 && abs(yy-cy)<2 && abs(xx-cx)<2) continue;  // shell only
      int c = (zz*GRES+yy)*GRES+xx;
      int s0 = starts[c], n = cnt[c];
      while (n > 0){
        int take = min(n, 64 - fill);
        if (lane >= fill && lane < fill + take){
          int s = s0 + lane - fill;
          float4 pc = pos4[s];
          int idx = pidx[s];
          float dot = __fmaf_rn(qz, pc.z, __fmaf_rn(qy, pc.y, __fmul_rn(qx, pc.x)));
          float d   = __fsub_rn(__fadd_rn(qsq, pc.w), __fmul_rn(2.0f, dot));
          unsigned su = __float_as_uint(d);
          su ^= (unsigned)((int)su >> 31) | 0x80000000u;
          pend = ((unsigned long long)su << 32) | (unsigned)idx;
        }
        fill += take; s0 += take; n -= take;
        if (fill == 64){ INSERT16(pend); pend = ~0ull; fill = 0; }
      }
    }
    INSERT16(pend); pend = ~0ull; fill = 0;
  }

  // ---- exact merge: 16 rounds of wave-min + winner shift ----
  unsigned long long kept = 0, m = 0;
  for (int j=0;j<16;++j){
    m = kk[0];
    #pragma unroll
    for (int o=1;o<64;o<<=1){
      unsigned long long ot = __shfl_xor(m, o, 64);
      m = (ot < m) ? ot : m;
    }
    if (lane == j) kept = m;
    if (kk[0] == m){
      #pragma unroll
      for (int p=0;p<15;++p) kk[p] = kk[p+1];
      kk[15] = ~0ull;
    }
  }
  if (lane < 16) ind[row*KNB + lane] = (int)(unsigned)(kept & 0xffffffffu);

  // ---- exact termination check on the scanned region; flag failures ----
  int R = need2 ? 2 : 1;
  float b16 = unsort_f((unsigned)(m >> 32));   // 16th-best d2 (NaN if <16 found)
  double mg = 1.0e300;
  double dqx=(double)qx, dqy=(double)qy, dqz=(double)qz;
  const double h = 0.125;
  if (cx-R > 0)      mg = fmin(mg, dqx - (double)(cx-R)*h);
  if (cx+R < GRES-1) mg = fmin(mg, (double)(cx+R+1)*h - dqx);
  if (cy-R > 0)      mg = fmin(mg, dqy - (double)(cy-R)*h);
  if (cy+R < GRES-1) mg = fmin(mg, (double)(cy+R+1)*h - dqy);
  if (cz-R > 0)      mg = fmin(mg, dqz - (double)(cz-R)*h);
  if (cz+R < GRES-1) mg = fmin(mg, (double)(cz+R+1)*h - dqz);
  bool ok = (mg*mg > (double)b16 + 1.0e-5);    // false on NaN -> flagged
  if (lane == 0) flags[t] = ok ? 0 : 1;
}

// Exact serial fallback (ring expansion to full grid) for flagged points only.
__global__ __launch_bounds__(256) void knn_fallback(const float4* __restrict__ pos4, const int* __restrict__ pidx,
                                                    const int* __restrict__ starts, const int* __restrict__ cnt,
                                                    const char* __restrict__ flags, int* __restrict__ ind){
  int t = blockIdx.x*256 + threadIdx.x;
  if (t >= N_PTS || !flags[t]) return;
  float4 qp = pos4[t];
  int row = pidx[t];
  float qx = qp.x, qy = qp.y, qz = qp.z, qsq = qp.w;
  int cx = min(GRES-1, max(0,(int)(qx*(float)GRES)));
  int cy = min(GRES-1, max(0,(int)(qy*(float)GRES)));
  int cz = min(GRES-1, max(0,(int)(qz*(float)GRES)));
  float bd[KNB]; int bi[KNB];
  #pragma unroll
  for (int k=0;k<KNB;++k){ bd[k] = 3.0e38f; bi[k] = 0x7fffffff; }
  const double cinv = 0.125;
  for (int r = 0; r < GRES; ++r){
    int zlo = max(0, cz-r), zhi = min(GRES-1, cz+r);
    int ylo = max(0, cy-r), yhi = min(GRES-1, cy+r);
    int xlo = max(0, cx-r), xhi = min(GRES-1, cx+r);
    for (int zz = zlo; zz <= zhi; ++zz){
      for (int yy = ylo; yy <= yhi; ++yy){
        for (int xx = xlo; xx <= xhi; ++xx){
          int ring = max(abs(zz-cz), max(abs(yy-cy), abs(xx-cx)));
          if (ring != r) continue;
          int c = (zz*GRES+yy)*GRES+xx;
          int s0 = starts[c], e = s0 + cnt[c];
          for (int s = s0; s < e; ++s){
            float4 pc = pos4[s];
            int idx = pidx[s];
            float dot = __fmaf_rn(qz, pc.z, __fmaf_rn(qy, pc.y, __fmul_rn(qx, pc.x)));
            float d   = __fsub_rn(__fadd_rn(qsq, pc.w), __fmul_rn(2.0f, dot));
            bool adm = (d < bd[KNB-1]) || (d == bd[KNB-1] && idx < bi[KNB-1]);
            if (adm){
              #pragma unroll
              for (int p = KNB-1; p >= 1; --p){
                float pd = bd[p-1]; int pi = bi[p-1];
                bool sh  = (pd > d) || (pd == d && pi > idx);
                bool ins = (!sh) && ((bd[p] > d) || (bd[p] == d && bi[p] > idx));
                bd[p] = sh ? pd : (ins ? d   : bd[p]);
                bi[p] = sh ? pi : (ins ? idx : bi[p]);
              }
              bool s0b = (bd[0] > d) || (bd[0] == d && bi[0] > idx);
              if (s0b){ bd[0] = d; bi[0] = idx; }
            }
          }
        }
      }
    }
    if (bd[KNB-1] < 3.0e37f){
      double mg = 1.0e300;
      double dqx=(double)qx, dqy=(double)qy, dqz=(double)qz;
      if (cx - r > 0)      mg = fmin(mg, dqx - (double)(cx-r)*cinv);
      if (cx + r < GRES-1) mg = fmin(mg, (double)(cx+r+1)*cinv - dqx);
      if (cy - r > 0)      mg = fmin(mg, dqy - (double)(cy-r)*cinv);
      if (cy + r < GRES-1) mg = fmin(mg, (double)(cy+r+1)*cinv - dqy);
      if (cz - r > 0)      mg = fmin(mg, dqz - (double)(cz-r)*cinv);
      if (cz + r < GRES-1) mg = fmin(mg, (double)(cz+r+1)*cinv - dqz);
      if (mg*mg > (double)bd[KNB-1] + 1.0e-5) break;
    }
  }
  #pragma unroll
  for (int k=0;k<KNB;++k) ind[row*KNB + k] = bi[k];
}

// ---------------- weight packing into B-fragment order ----------------
// B-frag (mfma_f32_16x16x32_bf16): lane l holds B[ks*32 + (l>>4)*8 + j][nt*16 + (l&15)], j=0..7
__global__ __launch_bounds__(256) void pack_kernel(const float* __restrict__ src, short* __restrict__ dst){
  int f = blockIdx.x*256 + threadIdx.x;     // 0..16383
  int j  = f & 7;
  int ln = (f >> 3) & 63;
  int ks = (f >> 9) & 3;
  int nt = f >> 11;
  int k = ks*32 + ((ln >> 4) << 3) + j;
  int n = nt*16 + (ln & 15);
  dst[f] = (short)f2b(src[k*DIMF + n]);
}

// ---------------- proj: q = x@Wq, xk = x@Wk, xv = x@Wv ----------------
__global__ __launch_bounds__(256) void proj_kernel(const float* __restrict__ x, const short* __restrict__ pw,
                                                   float* __restrict__ q, float* __restrict__ xk, float* __restrict__ xv){
  __shared__ __align__(16) char Abuf[32768];
  int tid = threadIdx.x, lane = tid & 63, wv = tid >> 6;
  int r0 = blockIdx.x * 128;
  {
    int row = tid >> 1, half = tid & 1;
    const float* xr = x + (size_t)(r0 + row)*DIMF + half*64;
    #pragma unroll
    for (int i=0;i<8;++i){
      bf16x8 v;
      #pragma unroll
      for (int j=0;j<8;++j) v[j] = (short)f2b(xr[i*8 + j]);
      *(bf16x8*)(&Abuf[row*256 + ((half*128 + i*16) ^ ((row&7)<<4))]) = v;
    }
  }
  __syncthreads();
  #pragma unroll 1
  for (int w = 0; w < 3; ++w){
    const bf16x8* bw = (const bf16x8*)(pw + w*16384);
    float* dst = (w==0) ? q : (w==1) ? xk : xv;
    f32x4 acc[2][8];
    #pragma unroll
    for (int i=0;i<2;++i)
      #pragma unroll
      for (int nt=0;nt<8;++nt) acc[i][nt] = (f32x4){0.f,0.f,0.f,0.f};
    #pragma unroll
    for (int ks=0;ks<4;++ks){
      int ra = (wv*2)*16 + (lane&15);
      int rb = (wv*2+1)*16 + (lane&15);
      int cb = ks*64 + ((lane>>4)<<4);
      bf16x8 a0 = *(const bf16x8*)(&Abuf[ra*256 + (cb ^ ((ra&7)<<4))]);
      bf16x8 a1 = *(const bf16x8*)(&Abuf[rb*256 + (cb ^ ((rb&7)<<4))]);
      #pragma unroll
      for (int nt=0;nt<8;++nt){
        bf16x8 b = bw[(nt*4+ks)*64 + lane];
        acc[0][nt] = __builtin_amdgcn_mfma_f32_16x16x32_bf16(a0, b, acc[0][nt], 0, 0, 0);
        acc[1][nt] = __builtin_amdgcn_mfma_f32_16x16x32_bf16(a1, b, acc[1][nt], 0, 0, 0);
      }
    }
    #pragma unroll
    for (int i=0;i<2;++i){
      int mt = wv*2+i;
      #pragma unroll
      for (int nt=0;nt<8;++nt){
        #pragma unroll
        for (int r=0;r<4;++r){
          int grow = r0 + mt*16 + ((lane>>4)<<2) + r;
          dst[(size_t)grow*DIMF + nt*16 + (lane&15)] = acc[i][nt][r];
        }
      }
    }
  }
}

// ---------------- fused main kernel: 8 points / wg ----------------
__global__ __launch_bounds__(256) void main_kernel(
    const float* __restrict__ x, const float* __restrict__ pos,
    const float* __restrict__ pe_w1, const float* __restrict__ pe_b1, const float* __restrict__ pe_b2,
    const float* __restrict__ mid_b1, const float* __restrict__ mid_b2,
    const float* __restrict__ fin_w, const float* __restrict__ fin_b,
    const float* __restrict__ qarr, const float* __restrict__ xkarr, const float* __restrict__ xvarr,
    const int* __restrict__ ind, const short* __restrict__ pw,
    float* __restrict__ out)
{
  __shared__ __align__(16) char Abuf[32768];
  __shared__ float aggbuf[8][DIMF];
  __shared__ int indbuf[128];
  int tid = threadIdx.x;
  int lane = tid & 63;
  int wv = tid >> 6;
  int p0 = blockIdx.x * 8;

  // Phase A: t = relu(rel @ pe_w1 + pe_b1) -> Abuf (bf16, swizzled)
  {
    int row = tid >> 1, half = tid & 1;
    int pt = p0 + (row >> 4);
    int nbr = ind[pt*KNB + (row & 15)];
    if (half == 0) indbuf[row] = nbr;
    float rx = pos[pt*3+0] - pos[nbr*3+0];
    float ry = pos[pt*3+1] - pos[nbr*3+1];
    float rz = pos[pt*3+2] - pos[nbr*3+2];
    const float4* w0 = (const float4*)(pe_w1);
    const float4* w1 = (const float4*)(pe_w1 + DIMF);
    const float4* w2 = (const float4*)(pe_w1 + 2*DIMF);
    const float4* bb = (const float4*)(pe_b1);
    #pragma unroll
    for (int i=0;i<8;++i){
      int c4 = half*16 + i*2;
      float4 va0 = w0[c4], va1 = w0[c4+1];
      float4 vb0 = w1[c4], vb1 = w1[c4+1];
      float4 vc0 = w2[c4], vc1 = w2[c4+1];
      float4 vd0 = bb[c4], vd1 = bb[c4+1];
      bf16x8 v;
      float tv;
      tv = fmaf(rx,va0.x,fmaf(ry,vb0.x,fmaf(rz,vc0.x,vd0.x))); v[0]=(short)f2b(fmaxf(tv,0.f));
      tv = fmaf(rx,va0.y,fmaf(ry,vb0.y,fmaf(rz,vc0.y,vd0.y))); v[1]=(short)f2b(fmaxf(tv,0.f));
      tv = fmaf(rx,va0.z,fmaf(ry,vb0.z,fmaf(rz,vc0.z,vd0.z))); v[2]=(short)f2b(fmaxf(tv,0.f));
      tv = fmaf(rx,va0.w,fmaf(ry,vb0.w,fmaf(rz,vc0.w,vd0.w))); v[3]=(short)f2b(fmaxf(tv,0.f));
      tv = fmaf(rx,va1.x,fmaf(ry,vb1.x,fmaf(rz,vc1.x,vd1.x))); v[4]=(short)f2b(fmaxf(tv,0.f));
      tv = fmaf(rx,va1.y,fmaf(ry,vb1.y,fmaf(rz,vc1.y,vd1.y))); v[5]=(short)f2b(fmaxf(tv,0.f));
      tv = fmaf(rx,va1.z,fmaf(ry,vb1.z,fmaf(rz,vc1.z,vd1.z))); v[6]=(short)f2b(fmaxf(tv,0.f));
      tv = fmaf(rx,va1.w,fmaf(ry,vb1.w,fmaf(rz,vc1.w,vd1.w))); v[7]=(short)f2b(fmaxf(tv,0.f));
      *(bf16x8*)(&Abuf[row*256 + ((half*128 + i*16) ^ ((row&7)<<4))]) = v;
    }
  }
  __syncthreads();

  f32x4 zreg[2][8];

  // GEMM1: pe = t @ pe_w2 + pe_b2 ; then h -> Abuf, z -> zreg
  {
    const bf16x8* bw = (const bf16x8*)(pw + 3*16384);
    f32x4 acc[2][8];
    #pragma unroll
    for (int nt=0;nt<8;++nt){
      float bv = pe_b2[nt*16 + (lane&15)];
      f32x4 iv = {bv,bv,bv,bv};
      acc[0][nt] = iv; acc[1][nt] = iv;
    }
    #pragma unroll
    for (int ks=0;ks<4;++ks){
      int ra = (wv*2)*16 + (lane&15);
      int rb = (wv*2+1)*16 + (lane&15);
      int cb = ks*64 + ((lane>>4)<<4);
      bf16x8 a0 = *(const bf16x8*)(&Abuf[ra*256 + (cb ^ ((ra&7)<<4))]);
      bf16x8 a1 = *(const bf16x8*)(&Abuf[rb*256 + (cb ^ ((rb&7)<<4))]);
      #pragma unroll
      for (int nt=0;nt<8;++nt){
        bf16x8 b = bw[(nt*4+ks)*64 + lane];
        acc[0][nt] = __builtin_amdgcn_mfma_f32_16x16x32_bf16(a0, b, acc[0][nt], 0, 0, 0);
        acc[1][nt] = __builtin_amdgcn_mfma_f32_16x16x32_bf16(a1, b, acc[1][nt], 0, 0, 0);
      }
    }
    __syncthreads();   // everyone done reading t
    #pragma unroll
    for (int i=0;i<2;++i){
      int mt = wv*2+i, ptg = p0+mt;
      int nbrs[4];
      #pragma unroll
      for (int r=0;r<4;++r) nbrs[r] = indbuf[mt*16 + ((lane>>4)<<2) + r];
      #pragma unroll
      for (int nt=0;nt<8;++nt){
        int col = nt*16 + (lane&15);
        float qv = qarr[(size_t)ptg*DIMF + col];
        #pragma unroll
        for (int r=0;r<4;++r){
          float pe = acc[i][nt][r];
          float hv = qv - xkarr[(size_t)nbrs[r]*DIMF + col] + pe;
          zreg[i][nt][r] = xvarr[(size_t)nbrs[r]*DIMF + col] + pe;
          int rowg = mt*16 + ((lane>>4)<<2) + r;
          *(short*)(&Abuf[rowg*256 + ((col*2) ^ ((rowg&7)<<4))]) = (short)f2b(hv);
        }
      }
    }
  }
  __syncthreads();

  // GEMM2: u = relu(h @ mid_w1 + mid_b1) -> Abuf
  {
    const bf16x8* bw = (const bf16x8*)(pw + 4*16384);
    f32x4 acc[2][8];
    #pragma unroll
    for (int nt=0;nt<8;++nt){
      float bv = mid_b1[nt*16 + (lane&15)];
      f32x4 iv = {bv,bv,bv,bv};
      acc[0][nt] = iv; acc[1][nt] = iv;
    }
    #pragma unroll
    for (int ks=0;ks<4;++ks){
      int ra = (wv*2)*16 + (lane&15);
      int rb = (wv*2+1)*16 + (lane&15);
      int cb = ks*64 + ((lane>>4)<<4);
      bf16x8 a0 = *(const bf16x8*)(&Abuf[ra*256 + (cb ^ ((ra&7)<<4))]);
      bf16x8 a1 = *(const bf16x8*)(&Abuf[rb*256 + (cb ^ ((rb&7)<<4))]);
      #pragma unroll
      for (int nt=0;nt<8;++nt){
        bf16x8 b = bw[(nt*4+ks)*64 + lane];
        acc[0][nt] = __builtin_amdgcn_mfma_f32_16x16x32_bf16(a0, b, acc[0][nt], 0, 0, 0);
        acc[1][nt] = __builtin_amdgcn_mfma_f32_16x16x32_bf16(a1, b, acc[1][nt], 0, 0, 0);
      }
    }
    __syncthreads();   // everyone done reading h
    #pragma unroll
    for (int i=0;i<2;++i){
      int mt = wv*2+i;
      #pragma unroll
      for (int nt=0;nt<8;++nt){
        int col = nt*16 + (lane&15);
        #pragma unroll
        for (int r=0;r<4;++r){
          int rowg = mt*16 + ((lane>>4)<<2) + r;
          *(short*)(&Abuf[rowg*256 + ((col*2) ^ ((rowg&7)<<4))]) = (short)f2b(fmaxf(acc[i][nt][r], 0.f));
        }
      }
    }
  }
  __syncthreads();

  // GEMM3: y = u @ mid_w2 + mid_b2 ; softmax over K; agg = sum(y_sm * z)
  {
    const bf16x8* bw = (const bf16x8*)(pw + 5*16384);
    f32x4 acc[2][8];
    #pragma unroll
    for (int nt=0;nt<8;++nt){
      float bv = mid_b2[nt*16 + (lane&15)];
      f32x4 iv = {bv,bv,bv,bv};
      acc[0][nt] = iv; acc[1][nt] = iv;
    }
    #pragma unroll
    for (int ks=0;ks<4;++ks){
      int ra = (wv*2)*16 + (lane&15);
      int rb = (wv*2+1)*16 + (lane&15);
      int cb = ks*64 + ((lane>>4)<<4);
      bf16x8 a0 = *(const bf16x8*)(&Abuf[ra*256 + (cb ^ ((ra&7)<<4))]);
      bf16x8 a1 = *(const bf16x8*)(&Abuf[rb*256 + (cb ^ ((rb&7)<<4))]);
      #pragma unroll
      for (int nt=0;nt<8;++nt){
        bf16x8 b = bw[(nt*4+ks)*64 + lane];
        acc[0][nt] = __builtin_amdgcn_mfma_f32_16x16x32_bf16(a0, b, acc[0][nt], 0, 0, 0);
        acc[1][nt] = __builtin_amdgcn_mfma_f32_16x16x32_bf16(a1, b, acc[1][nt], 0, 0, 0);
      }
    }
    const float invS = 0.08838834764831843f;   // 1/sqrt(128)
    #pragma unroll
    for (int i=0;i<2;++i){
      int mt = wv*2+i;
      #pragma unroll
      for (int nt=0;nt<8;++nt){
        f32x4 y = acc[i][nt];
        float mx = fmaxf(fmaxf(y[0],y[1]), fmaxf(y[2],y[3]));
        mx = fmaxf(mx, __shfl_xor(mx, 16, 64));
        mx = fmaxf(mx, __shfl_xor(mx, 32, 64));
        float e0 = __expf((y[0]-mx)*invS);
        float e1 = __expf((y[1]-mx)*invS);
        float e2 = __expf((y[2]-mx)*invS);
        float e3 = __expf((y[3]-mx)*invS);
        float ssum = e0+e1+e2+e3;
        ssum += __shfl_xor(ssum, 16, 64);
        ssum += __shfl_xor(ssum, 32, 64);
        f32x4 zz = zreg[i][nt];
        float ps = (e0*zz[0] + e1*zz[1] + e2*zz[2] + e3*zz[3]) / ssum;
        ps += __shfl_xor(ps, 16, 64);
        ps += __shfl_xor(ps, 32, 64);
        if (lane < 16) aggbuf[mt][nt*16 + lane] = ps;
      }
    }
  }
  __syncthreads();

  // Final: out = agg @ fin_w + fin_b + x
  {
    int c = tid & 127;
    int pg = tid >> 7;  // 0 or 1 -> points pg*4 .. pg*4+3
    float fb = fin_b[c];
    float a0 = fb, a1 = fb, a2 = fb, a3 = fb;
    for (int d = 0; d < DIMF; ++d){
      float wvv = fin_w[d*DIMF + c];
      a0 = fmaf(aggbuf[pg*4+0][d], wvv, a0);
      a1 = fmaf(aggbuf[pg*4+1][d], wvv, a1);
      a2 = fmaf(aggbuf[pg*4+2][d], wvv, a2);
      a3 = fmaf(aggbuf[pg*4+3][d], wvv, a3);
    }
    size_t base0 = (size_t)(p0 + pg*4)*DIMF + c;
    out[base0 + 0*DIMF] = a0 + x[base0 + 0*DIMF];
    out[base0 + 1*DIMF] = a1 + x[base0 + 1*DIMF];
    out[base0 + 2*DIMF] = a2 + x[base0 + 2*DIMF];
    out[base0 + 3*DIMF] = a3 + x[base0 + 3*DIMF];
  }
}

extern "C" void kernel_launch(void* const* d_in, const int* in_sizes, int n_in,
                              void* d_out, int out_size, void* d_ws, size_t ws_size,
                              hipStream_t stream)
{
  (void)in_sizes; (void)n_in; (void)out_size; (void)ws_size;
  const float* x      = (const float*)d_in[0];
  const float* pos    = (const float*)d_in[1];
  const float* Wq     = (const float*)d_in[2];
  const float* Wk     = (const float*)d_in[3];
  const float* Wv     = (const float*)d_in[4];
  const float* mid_w1 = (const float*)d_in[5];
  const float* mid_b1 = (const float*)d_in[6];
  const float* mid_w2 = (const float*)d_in[7];
  const float* mid_b2 = (const float*)d_in[8];
  const float* pe_w1  = (const float*)d_in[9];
  const float* pe_b1  = (const float*)d_in[10];
  const float* pe_w2  = (const float*)d_in[11];
  const float* pe_b2  = (const float*)d_in[12];
  const float* fin_w  = (const float*)d_in[13];
  const float* fin_b  = (const float*)d_in[14];
  float* out = (float*)d_out;
  char* ws = (char*)d_ws;

  int*    cellcnt = (int*)   (ws + 0);         //  2 KB (512 cells)
  int*    fillp   = (int*)   (ws + 4096);      //  2 KB
  int*    starts  = (int*)   (ws + 16384);     //  2 KB
  char*   flags   = (char*)  (ws + 18432);     // 16 KB
  int*    pidx    = (int*)   (ws + 49152);     //  64 KB
  float4* pos4    = (float4*)(ws + 114688);    // 256 KB
  int*    ind     = (int*)   (ws + 376832);    //   1 MB
  short*  pw      = (short*) (ws + 1425408);   // 192 KB (6 packed 128x128 bf16 weights)
  float*  qarr    = (float*) (ws + 1622016);   //   8 MB
  float*  xkarr   = (float*) (ws + 10010624);  //   8 MB
  float*  xvarr   = (float*) (ws + 18399232);  //   8 MB  (end ~25.6 MB)

  hipMemsetAsync(cellcnt, 0, NCELL*sizeof(int), stream);
  count_kernel  <<<N_PTS/256, 256, 0, stream>>>(pos, cellcnt);
  scan_kernel   <<<1,         256, 0, stream>>>(cellcnt, starts, fillp);
  scatter_kernel<<<N_PTS/256, 256, 0, stream>>>(pos, fillp, pos4, pidx);
  knn_query64   <<<N_PTS/4,   256, 0, stream>>>(pos4, pidx, starts, cellcnt, ind, flags);
  knn_fallback  <<<N_PTS/256, 256, 0, stream>>>(pos4, pidx, starts, cellcnt, flags, ind);

  pack_kernel<<<64, 256, 0, stream>>>(Wq,     pw + 0*16384);
  pack_kernel<<<64, 256, 0, stream>>>(Wk,     pw + 1*16384);
  pack_kernel<<<64, 256, 0, stream>>>(Wv,     pw + 2*16384);
  pack_kernel<<<64, 256, 0, stream>>>(pe_w2,  pw + 3*16384);
  pack_kernel<<<64, 256, 0, stream>>>(mid_w1, pw + 4*16384);
  pack_kernel<<<64, 256, 0, stream>>>(mid_w2, pw + 5*16384);

  proj_kernel<<<N_PTS/128, 256, 0, stream>>>(x, pw, qarr, xkarr, xvarr);

  main_kernel<<<N_PTS/8, 256, 0, stream>>>(x, pos, pe_w1, pe_b1, pe_b2, mid_b1, mid_b2,
                                           fin_w, fin_b, qarr, xkarr, xvarr, ind, pw, out);
}

// Round 6
// 327.905 us; speedup vs baseline: 1.6754x; 1.6754x over previous
//
#include <hip/hip_runtime.h>
#include <hip/hip_bf16.h>

#define N_PTS 16384
#define DIMF  128
#define KNB   16
#define GRES  8
#define NCELL (GRES*GRES*GRES)

typedef __attribute__((ext_vector_type(8))) short bf16x8;
typedef __attribute__((ext_vector_type(4))) float f32x4;

__device__ __forceinline__ unsigned short f2b(float f){
  unsigned int u = __float_as_uint(f);
  u = u + 0x7fffu + ((u >> 16) & 1u);
  return (unsigned short)(u >> 16);
}

__device__ __forceinline__ float unsort_f(unsigned s){
  unsigned u = (s & 0x80000000u) ? (s ^ 0x80000000u) : ~s;
  return __uint_as_float(u);
}

// ---------------- KNN: grid build (GRES=8, 512 cells) ----------------
__global__ __launch_bounds__(256) void count_kernel(const float* __restrict__ pos, int* __restrict__ cnt){
  int i = blockIdx.x*256 + threadIdx.x;
  float px = pos[i*3+0], py = pos[i*3+1], pz = pos[i*3+2];
  int cx = min(GRES-1, max(0,(int)(px*(float)GRES)));
  int cy = min(GRES-1, max(0,(int)(py*(float)GRES)));
  int cz = min(GRES-1, max(0,(int)(pz*(float)GRES)));
  atomicAdd(&cnt[(cz*GRES+cy)*GRES+cx], 1);
}

__global__ __launch_bounds__(256) void scan_kernel(const int* __restrict__ cnt, int* __restrict__ starts, int* __restrict__ fillp){
  __shared__ int part[256];
  int t = threadIdx.x;
  int a = cnt[2*t], b = cnt[2*t+1];
  part[t] = a + b;
  __syncthreads();
  if (t == 0){
    int acc = 0;
    for (int i=0;i<256;++i){ int tmp = part[i]; part[i] = acc; acc += tmp; }
  }
  __syncthreads();
  int base = part[t];
  starts[2*t]   = base;     fillp[2*t]   = base;
  starts[2*t+1] = base + a; fillp[2*t+1] = base + a;
}

// sq stored numpy-style: ((x*x + y*y) + z*z), each op separately f32-rounded (no contraction)
__global__ __launch_bounds__(256) void scatter_kernel(const float* __restrict__ pos, int* __restrict__ fillp,
                                                      float4* __restrict__ pos4, int* __restrict__ pidx){
  int i = blockIdx.x*256 + threadIdx.x;
  float px = pos[i*3+0], py = pos[i*3+1], pz = pos[i*3+2];
  int cx = min(GRES-1, max(0,(int)(px*(float)GRES)));
  int cy = min(GRES-1, max(0,(int)(py*(float)GRES)));
  int cz = min(GRES-1, max(0,(int)(pz*(float)GRES)));
  int c = (cz*GRES+cy)*GRES+cx;
  float sq = __fadd_rn(__fadd_rn(__fmul_rn(px,px), __fmul_rn(py,py)), __fmul_rn(pz,pz));
  int s = atomicAdd(&fillp[c], 1);
  pos4[s] = make_float4(px, py, pz, sq);
  pidx[s] = i;
}

// One wave per point. Exact top-16 by (d2, idx) with d2 replicating numpy f32
// bit-exactly. Threshold filter tau^2 (exact whenever admitted count>=16:
// any candidate with d2>=tau^2 is lex-greater than >=16 admitted ones, so the
// true top-16 is a subset of the admitted set) -> ballot-compact to LDS ->
// one 64-key bitonic sort. Retry loop adapts tau; geometric ring-1 bound
// checked against the true 16th; failures flagged for the exact fallback.
__global__ __launch_bounds__(256) void knn_query64(const float4* __restrict__ pos4, const int* __restrict__ pidx,
                                                   const int* __restrict__ starts, const int* __restrict__ cnt,
                                                   int* __restrict__ ind, char* __restrict__ flags){
  __shared__ unsigned long long cand[4][64];
  int lane = threadIdx.x & 63;
  int wv   = threadIdx.x >> 6;
  int t = blockIdx.x*4 + wv;
  float4 qp = pos4[t];
  int row = pidx[t];
  float qx = qp.x, qy = qp.y, qz = qp.z, qsq = qp.w;
  int cx = min(GRES-1, max(0,(int)(qx*(float)GRES)));
  int cy = min(GRES-1, max(0,(int)(qy*(float)GRES)));
  int cz = min(GRES-1, max(0,(int)(qz*(float)GRES)));
  int zlo = max(0,cz-1), zhi = min(GRES-1,cz+1);
  int ylo = max(0,cy-1), yhi = min(GRES-1,cy+1);
  int xlo = max(0,cx-1), xhi = min(GRES-1,cx+1);

  // ---- local density -> initial tau^2 ----
  int nb = 0;
  if (lane < 27){
    int dz = lane/9 - 1, dy = (lane/3)%3 - 1, dx = lane%3 - 1;
    int zz = cz+dz, yy = cy+dy, xx = cx+dx;
    if (zz>=zlo && zz<=zhi && yy>=ylo && yy<=yhi && xx>=xlo && xx<=xhi)
      nb = cnt[(zz*GRES+yy)*GRES+xx];
  }
  #pragma unroll
  for (int o=1;o<64;o<<=1) nb += __shfl_xor(nb, o, 64);
  float V = (float)((zhi-zlo+1)*(yhi-ylo+1)*(xhi-xlo+1)) * 0.001953125f;  // cells * h^3
  float r3 = 3.8197186f * V / (float)nb;           // r16^3 under uniform density
  float tau2 = 2.0f * __powf(r3, 0.66666667f);     // safety c=2.0 -> E[n]~45

  // ---- filtered scan with adaptive retry ----
  int nfound = 0;
  bool okscan = false;
  for (int it = 0; it < 8; ++it){
    nfound = 0;
    for (int zz=zlo; zz<=zhi; ++zz)
    for (int yy=ylo; yy<=yhi; ++yy)
    for (int xx=xlo; xx<=xhi; ++xx){
      int c = (zz*GRES+yy)*GRES+xx;
      int s0 = starts[c], n = cnt[c];
      for (int b = 0; b < n; b += 64){
        int o = b + lane;
        bool valid = o < n;
        float d = 3.0e38f; int idx = 0;
        if (valid){
          float4 pc = pos4[s0+o];
          idx = pidx[s0+o];
          float dot = __fmaf_rn(qz, pc.z, __fmaf_rn(qy, pc.y, __fmul_rn(qx, pc.x)));
          d   = __fsub_rn(__fadd_rn(qsq, pc.w), __fmul_rn(2.0f, dot));
        }
        bool admit = valid && (d < tau2);
        unsigned long long mask = __ballot(admit);
        if (admit){
          int pos = nfound + (int)__popcll(mask & ((1ull<<lane)-1ull));
          if (pos < 64){
            unsigned su = __float_as_uint(d);
            su ^= (unsigned)((int)su >> 31) | 0x80000000u;
            cand[wv][pos] = ((unsigned long long)su << 32) | (unsigned)idx;
          }
        }
        nfound += (int)__popcll(mask);
      }
    }
    if (nfound > 64){ tau2 *= 0.7f; continue; }
    if (nfound < 16){ tau2 *= 2.0f; continue; }
    okscan = true; break;
  }
  if (!okscan){ if (lane == 0) flags[t] = 1; return; }

  asm volatile("s_waitcnt lgkmcnt(0)" ::: "memory");
  __builtin_amdgcn_sched_barrier(0);
  unsigned long long key = (lane < nfound) ? cand[wv][lane] : ~0ull;

  // ---- bitonic sort of 64 keys across the wave (ascending) ----
  #pragma unroll
  for (int k = 2; k <= 64; k <<= 1){
    #pragma unroll
    for (int j = k>>1; j >= 1; j >>= 1){
      unsigned long long other = __shfl_xor(key, j, 64);
      bool takeSmall = (((lane & k) == 0) != ((lane & j) != 0));
      bool less = other < key;
      key = (takeSmall == less) ? other : key;
    }
  }
  if (lane < 16) ind[row*KNB + lane] = (int)(unsigned)(key & 0xffffffffu);

  // ---- geometric termination (ring-1 box) vs true 16th; flag failures ----
  unsigned long long k15 = __shfl(key, 15, 64);
  float b16 = unsort_f((unsigned)(k15 >> 32));
  double mg = 1.0e300;
  double dqx=(double)qx, dqy=(double)qy, dqz=(double)qz;
  const double h = 0.125;
  if (cx-1 > 0)      mg = fmin(mg, dqx - (double)(cx-1)*h);
  if (cx+1 < GRES-1) mg = fmin(mg, (double)(cx+2)*h - dqx);
  if (cy-1 > 0)      mg = fmin(mg, dqy - (double)(cy-1)*h);
  if (cy+1 < GRES-1) mg = fmin(mg, (double)(cy+2)*h - dqy);
  if (cz-1 > 0)      mg = fmin(mg, dqz - (double)(cz-1)*h);
  if (cz+1 < GRES-1) mg = fmin(mg, (double)(cz+2)*h - dqz);
  bool ok = (mg*mg > (double)b16 + 1.0e-5);
  if (lane == 0) flags[t] = ok ? 0 : 1;
}

// Exact serial fallback (ring expansion to full grid) for flagged points only.
__global__ __launch_bounds__(256) void knn_fallback(const float4* __restrict__ pos4, const int* __restrict__ pidx,
                                                    const int* __restrict__ starts, const int* __restrict__ cnt,
                                                    const char* __restrict__ flags, int* __restrict__ ind){
  int t = blockIdx.x*256 + threadIdx.x;
  if (t >= N_PTS || !flags[t]) return;
  float4 qp = pos4[t];
  int row = pidx[t];
  float qx = qp.x, qy = qp.y, qz = qp.z, qsq = qp.w;
  int cx = min(GRES-1, max(0,(int)(qx*(float)GRES)));
  int cy = min(GRES-1, max(0,(int)(qy*(float)GRES)));
  int cz = min(GRES-1, max(0,(int)(qz*(float)GRES)));
  float bd[KNB]; int bi[KNB];
  #pragma unroll
  for (int k=0;k<KNB;++k){ bd[k] = 3.0e38f; bi[k] = 0x7fffffff; }
  const double cinv = 0.125;
  for (int r = 0; r < GRES; ++r){
    int zlo = max(0, cz-r), zhi = min(GRES-1, cz+r);
    int ylo = max(0, cy-r), yhi = min(GRES-1, cy+r);
    int xlo = max(0, cx-r), xhi = min(GRES-1, cx+r);
    for (int zz = zlo; zz <= zhi; ++zz){
      for (int yy = ylo; yy <= yhi; ++yy){
        for (int xx = xlo; xx <= xhi; ++xx){
          int ring = max(abs(zz-cz), max(abs(yy-cy), abs(xx-cx)));
          if (ring != r) continue;
          int c = (zz*GRES+yy)*GRES+xx;
          int s0 = starts[c], e = s0 + cnt[c];
          for (int s = s0; s < e; ++s){
            float4 pc = pos4[s];
            int idx = pidx[s];
            float dot = __fmaf_rn(qz, pc.z, __fmaf_rn(qy, pc.y, __fmul_rn(qx, pc.x)));
            float d   = __fsub_rn(__fadd_rn(qsq, pc.w), __fmul_rn(2.0f, dot));
            bool adm = (d < bd[KNB-1]) || (d == bd[KNB-1] && idx < bi[KNB-1]);
            if (adm){
              #pragma unroll
              for (int p = KNB-1; p >= 1; --p){
                float pd = bd[p-1]; int pi = bi[p-1];
                bool sh  = (pd > d) || (pd == d && pi > idx);
                bool ins = (!sh) && ((bd[p] > d) || (bd[p] == d && bi[p] > idx));
                bd[p] = sh ? pd : (ins ? d   : bd[p]);
                bi[p] = sh ? pi : (ins ? idx : bi[p]);
              }
              bool s0b = (bd[0] > d) || (bd[0] == d && bi[0] > idx);
              if (s0b){ bd[0] = d; bi[0] = idx; }
            }
          }
        }
      }
    }
    if (bd[KNB-1] < 3.0e37f){
      double mg = 1.0e300;
      double dqx=(double)qx, dqy=(double)qy, dqz=(double)qz;
      if (cx - r > 0)      mg = fmin(mg, dqx - (double)(cx-r)*cinv);
      if (cx + r < GRES-1) mg = fmin(mg, (double)(cx+r+1)*cinv - dqx);
      if (cy - r > 0)      mg = fmin(mg, dqy - (double)(cy-r)*cinv);
      if (cy + r < GRES-1) mg = fmin(mg, (double)(cy+r+1)*cinv - dqy);
      if (cz - r > 0)      mg = fmin(mg, dqz - (double)(cz-r)*cinv);
      if (cz + r < GRES-1) mg = fmin(mg, (double)(cz+r+1)*cinv - dqz);
      if (mg*mg > (double)bd[KNB-1] + 1.0e-5) break;
    }
  }
  #pragma unroll
  for (int k=0;k<KNB;++k) ind[row*KNB + k] = bi[k];
}

// ---------------- weight packing into B-fragment order (all 6 in one launch) ----------------
// B-frag (mfma_f32_16x16x32_bf16): lane l holds B[ks*32 + (l>>4)*8 + j][nt*16 + (l&15)], j=0..7
__global__ __launch_bounds__(256) void pack_all(const float* __restrict__ w0, const float* __restrict__ w1,
                                                const float* __restrict__ w2, const float* __restrict__ w3,
                                                const float* __restrict__ w4, const float* __restrict__ w5,
                                                short* __restrict__ dst){
  int slot = blockIdx.y;
  const float* src = (slot==0)?w0:(slot==1)?w1:(slot==2)?w2:(slot==3)?w3:(slot==4)?w4:w5;
  int f = blockIdx.x*256 + threadIdx.x;     // 0..16383
  int j  = f & 7;
  int ln = (f >> 3) & 63;
  int ks = (f >> 9) & 3;
  int nt = f >> 11;
  int k = ks*32 + ((ln >> 4) << 3) + j;
  int n = nt*16 + (ln & 15);
  dst[slot*16384 + f] = (short)f2b(src[k*DIMF + n]);
}

// ---------------- proj: q = x@Wq, xk = x@Wk, xv = x@Wv ----------------
__global__ __launch_bounds__(256) void proj_kernel(const float* __restrict__ x, const short* __restrict__ pw,
                                                   float* __restrict__ q, float* __restrict__ xk, float* __restrict__ xv){
  __shared__ __align__(16) char Abuf[32768];
  int tid = threadIdx.x, lane = tid & 63, wv = tid >> 6;
  int r0 = blockIdx.x * 128;
  {
    int row = tid >> 1, half = tid & 1;
    const float* xr = x + (size_t)(r0 + row)*DIMF + half*64;
    #pragma unroll
    for (int i=0;i<8;++i){
      bf16x8 v;
      #pragma unroll
      for (int j=0;j<8;++j) v[j] = (short)f2b(xr[i*8 + j]);
      *(bf16x8*)(&Abuf[row*256 + ((half*128 + i*16) ^ ((row&7)<<4))]) = v;
    }
  }
  __syncthreads();
  #pragma unroll 1
  for (int w = 0; w < 3; ++w){
    const bf16x8* bw = (const bf16x8*)(pw + w*16384);
    float* dst = (w==0) ? q : (w==1) ? xk : xv;
    f32x4 acc[2][8];
    #pragma unroll
    for (int i=0;i<2;++i)
      #pragma unroll
      for (int nt=0;nt<8;++nt) acc[i][nt] = (f32x4){0.f,0.f,0.f,0.f};
    #pragma unroll
    for (int ks=0;ks<4;++ks){
      int ra = (wv*2)*16 + (lane&15);
      int rb = (wv*2+1)*16 + (lane&15);
      int cb = ks*64 + ((lane>>4)<<4);
      bf16x8 a0 = *(const bf16x8*)(&Abuf[ra*256 + (cb ^ ((ra&7)<<4))]);
      bf16x8 a1 = *(const bf16x8*)(&Abuf[rb*256 + (cb ^ ((rb&7)<<4))]);
      #pragma unroll
      for (int nt=0;nt<8;++nt){
        bf16x8 b = bw[(nt*4+ks)*64 + lane];
        acc[0][nt] = __builtin_amdgcn_mfma_f32_16x16x32_bf16(a0, b, acc[0][nt], 0, 0, 0);
        acc[1][nt] = __builtin_amdgcn_mfma_f32_16x16x32_bf16(a1, b, acc[1][nt], 0, 0, 0);
      }
    }
    #pragma unroll
    for (int i=0;i<2;++i){
      int mt = wv*2+i;
      #pragma unroll
      for (int nt=0;nt<8;++nt){
        #pragma unroll
        for (int r=0;r<4;++r){
          int grow = r0 + mt*16 + ((lane>>4)<<2) + r;
          dst[(size_t)grow*DIMF + nt*16 + (lane&15)] = acc[i][nt][r];
        }
      }
    }
  }
}

// ---------------- fused main kernel: 8 points / wg ----------------
__global__ __launch_bounds__(256) void main_kernel(
    const float* __restrict__ x, const float* __restrict__ pos,
    const float* __restrict__ pe_w1, const float* __restrict__ pe_b1, const float* __restrict__ pe_b2,
    const float* __restrict__ mid_b1, const float* __restrict__ mid_b2,
    const float* __restrict__ fin_w, const float* __restrict__ fin_b,
    const float* __restrict__ qarr, const float* __restrict__ xkarr, const float* __restrict__ xvarr,
    const int* __restrict__ ind, const short* __restrict__ pw,
    float* __restrict__ out)
{
  __shared__ __align__(16) char Abuf[32768];
  __shared__ float aggbuf[8][DIMF];
  __shared__ int indbuf[128];
  int tid = threadIdx.x;
  int lane = tid & 63;
  int wv = tid >> 6;
  int p0 = blockIdx.x * 8;

  // Phase A: t = relu(rel @ pe_w1 + pe_b1) -> Abuf (bf16, swizzled)
  {
    int row = tid >> 1, half = tid & 1;
    int pt = p0 + (row >> 4);
    int nbr = ind[pt*KNB + (row & 15)];
    if (half == 0) indbuf[row] = nbr;
    float rx = pos[pt*3+0] - pos[nbr*3+0];
    float ry = pos[pt*3+1] - pos[nbr*3+1];
    float rz = pos[pt*3+2] - pos[nbr*3+2];
    const float4* w0 = (const float4*)(pe_w1);
    const float4* w1 = (const float4*)(pe_w1 + DIMF);
    const float4* w2 = (const float4*)(pe_w1 + 2*DIMF);
    const float4* bb = (const float4*)(pe_b1);
    #pragma unroll
    for (int i=0;i<8;++i){
      int c4 = half*16 + i*2;
      float4 va0 = w0[c4], va1 = w0[c4+1];
      float4 vb0 = w1[c4], vb1 = w1[c4+1];
      float4 vc0 = w2[c4], vc1 = w2[c4+1];
      float4 vd0 = bb[c4], vd1 = bb[c4+1];
      bf16x8 v;
      float tv;
      tv = fmaf(rx,va0.x,fmaf(ry,vb0.x,fmaf(rz,vc0.x,vd0.x))); v[0]=(short)f2b(fmaxf(tv,0.f));
      tv = fmaf(rx,va0.y,fmaf(ry,vb0.y,fmaf(rz,vc0.y,vd0.y))); v[1]=(short)f2b(fmaxf(tv,0.f));
      tv = fmaf(rx,va0.z,fmaf(ry,vb0.z,fmaf(rz,vc0.z,vd0.z))); v[2]=(short)f2b(fmaxf(tv,0.f));
      tv = fmaf(rx,va0.w,fmaf(ry,vb0.w,fmaf(rz,vc0.w,vd0.w))); v[3]=(short)f2b(fmaxf(tv,0.f));
      tv = fmaf(rx,va1.x,fmaf(ry,vb1.x,fmaf(rz,vc1.x,vd1.x))); v[4]=(short)f2b(fmaxf(tv,0.f));
      tv = fmaf(rx,va1.y,fmaf(ry,vb1.y,fmaf(rz,vc1.y,vd1.y))); v[5]=(short)f2b(fmaxf(tv,0.f));
      tv = fmaf(rx,va1.z,fmaf(ry,vb1.z,fmaf(rz,vc1.z,vd1.z))); v[6]=(short)f2b(fmaxf(tv,0.f));
      tv = fmaf(rx,va1.w,fmaf(ry,vb1.w,fmaf(rz,vc1.w,vd1.w))); v[7]=(short)f2b(fmaxf(tv,0.f));
      *(bf16x8*)(&Abuf[row*256 + ((half*128 + i*16) ^ ((row&7)<<4))]) = v;
    }
  }
  __syncthreads();

  f32x4 zreg[2][8];

  // GEMM1: pe = t @ pe_w2 + pe_b2 ; then h -> Abuf, z -> zreg
  {
    const bf16x8* bw = (const bf16x8*)(pw + 3*16384);
    f32x4 acc[2][8];
    #pragma unroll
    for (int nt=0;nt<8;++nt){
      float bv = pe_b2[nt*16 + (lane&15)];
      f32x4 iv = {bv,bv,bv,bv};
      acc[0][nt] = iv; acc[1][nt] = iv;
    }
    #pragma unroll
    for (int ks=0;ks<4;++ks){
      int ra = (wv*2)*16 + (lane&15);
      int rb = (wv*2+1)*16 + (lane&15);
      int cb = ks*64 + ((lane>>4)<<4);
      bf16x8 a0 = *(const bf16x8*)(&Abuf[ra*256 + (cb ^ ((ra&7)<<4))]);
      bf16x8 a1 = *(const bf16x8*)(&Abuf[rb*256 + (cb ^ ((rb&7)<<4))]);
      #pragma unroll
      for (int nt=0;nt<8;++nt){
        bf16x8 b = bw[(nt*4+ks)*64 + lane];
        acc[0][nt] = __builtin_amdgcn_mfma_f32_16x16x32_bf16(a0, b, acc[0][nt], 0, 0, 0);
        acc[1][nt] = __builtin_amdgcn_mfma_f32_16x16x32_bf16(a1, b, acc[1][nt], 0, 0, 0);
      }
    }
    __syncthreads();   // everyone done reading t
    #pragma unroll
    for (int i=0;i<2;++i){
      int mt = wv*2+i, ptg = p0+mt;
      int nbrs[4];
      #pragma unroll
      for (int r=0;r<4;++r) nbrs[r] = indbuf[mt*16 + ((lane>>4)<<2) + r];
      #pragma unroll
      for (int nt=0;nt<8;++nt){
        int col = nt*16 + (lane&15);
        float qv = qarr[(size_t)ptg*DIMF + col];
        #pragma unroll
        for (int r=0;r<4;++r){
          float pe = acc[i][nt][r];
          float hv = qv - xkarr[(size_t)nbrs[r]*DIMF + col] + pe;
          zreg[i][nt][r] = xvarr[(size_t)nbrs[r]*DIMF + col] + pe;
          int rowg = mt*16 + ((lane>>4)<<2) + r;
          *(short*)(&Abuf[rowg*256 + ((col*2) ^ ((rowg&7)<<4))]) = (short)f2b(hv);
        }
      }
    }
  }
  __syncthreads();

  // GEMM2: u = relu(h @ mid_w1 + mid_b1) -> Abuf
  {
    const bf16x8* bw = (const bf16x8*)(pw + 4*16384);
    f32x4 acc[2][8];
    #pragma unroll
    for (int nt=0;nt<8;++nt){
      float bv = mid_b1[nt*16 + (lane&15)];
      f32x4 iv = {bv,bv,bv,bv};
      acc[0][nt] = iv; acc[1][nt] = iv;
    }
    #pragma unroll
    for (int ks=0;ks<4;++ks){
      int ra = (wv*2)*16 + (lane&15);
      int rb = (wv*2+1)*16 + (lane&15);
      int cb = ks*64 + ((lane>>4)<<4);
      bf16x8 a0 = *(const bf16x8*)(&Abuf[ra*256 + (cb ^ ((ra&7)<<4))]);
      bf16x8 a1 = *(const bf16x8*)(&Abuf[rb*256 + (cb ^ ((rb&7)<<4))]);
      #pragma unroll
      for (int nt=0;nt<8;++nt){
        bf16x8 b = bw[(nt*4+ks)*64 + lane];
        acc[0][nt] = __builtin_amdgcn_mfma_f32_16x16x32_bf16(a0, b, acc[0][nt], 0, 0, 0);
        acc[1][nt] = __builtin_amdgcn_mfma_f32_16x16x32_bf16(a1, b, acc[1][nt], 0, 0, 0);
      }
    }
    __syncthreads();   // everyone done reading h
    #pragma unroll
    for (int i=0;i<2;++i){
      int mt = wv*2+i;
      #pragma unroll
      for (int nt=0;nt<8;++nt){
        int col = nt*16 + (lane&15);
        #pragma unroll
        for (int r=0;r<4;++r){
          int rowg = mt*16 + ((lane>>4)<<2) + r;
          *(short*)(&Abuf[rowg*256 + ((col*2) ^ ((rowg&7)<<4))]) = (short)f2b(fmaxf(acc[i][nt][r], 0.f));
        }
      }
    }
  }
  __syncthreads();

  // GEMM3: y = u @ mid_w2 + mid_b2 ; softmax over K; agg = sum(y_sm * z)
  {
    const bf16x8* bw = (const bf16x8*)(pw + 5*16384);
    f32x4 acc[2][8];
    #pragma unroll
    for (int nt=0;nt<8;++nt){
      float bv = mid_b2[nt*16 + (lane&15)];
      f32x4 iv = {bv,bv,bv,bv};
      acc[0][nt] = iv; acc[1][nt] = iv;
    }
    #pragma unroll
    for (int ks=0;ks<4;++ks){
      int ra = (wv*2)*16 + (lane&15);
      int rb = (wv*2+1)*16 + (lane&15);
      int cb = ks*64 + ((lane>>4)<<4);
      bf16x8 a0 = *(const bf16x8*)(&Abuf[ra*256 + (cb ^ ((ra&7)<<4))]);
      bf16x8 a1 = *(const bf16x8*)(&Abuf[rb*256 + (cb ^ ((rb&7)<<4))]);
      #pragma unroll
      for (int nt=0;nt<8;++nt){
        bf16x8 b = bw[(nt*4+ks)*64 + lane];
        acc[0][nt] = __builtin_amdgcn_mfma_f32_16x16x32_bf16(a0, b, acc[0][nt], 0, 0, 0);
        acc[1][nt] = __builtin_amdgcn_mfma_f32_16x16x32_bf16(a1, b, acc[1][nt], 0, 0, 0);
      }
    }
    const float invS = 0.08838834764831843f;   // 1/sqrt(128)
    #pragma unroll
    for (int i=0;i<2;++i){
      int mt = wv*2+i;
      #pragma unroll
      for (int nt=0;nt<8;++nt){
        f32x4 y = acc[i][nt];
        float mx = fmaxf(fmaxf(y[0],y[1]), fmaxf(y[2],y[3]));
        mx = fmaxf(mx, __shfl_xor(mx, 16, 64));
        mx = fmaxf(mx, __shfl_xor(mx, 32, 64));
        float e0 = __expf((y[0]-mx)*invS);
        float e1 = __expf((y[1]-mx)*invS);
        float e2 = __expf((y[2]-mx)*invS);
        float e3 = __expf((y[3]-mx)*invS);
        float ssum = e0+e1+e2+e3;
        ssum += __shfl_xor(ssum, 16, 64);
        ssum += __shfl_xor(ssum, 32, 64);
        f32x4 zz = zreg[i][nt];
        float ps = (e0*zz[0] + e1*zz[1] + e2*zz[2] + e3*zz[3]) / ssum;
        ps += __shfl_xor(ps, 16, 64);
        ps += __shfl_xor(ps, 32, 64);
        if (lane < 16) aggbuf[mt][nt*16 + lane] = ps;
      }
    }
  }
  __syncthreads();

  // Final: out = agg @ fin_w + fin_b + x
  {
    int c = tid & 127;
    int pg = tid >> 7;  // 0 or 1 -> points pg*4 .. pg*4+3
    float fb = fin_b[c];
    float a0 = fb, a1 = fb, a2 = fb, a3 = fb;
    for (int d = 0; d < DIMF; ++d){
      float wvv = fin_w[d*DIMF + c];
      a0 = fmaf(aggbuf[pg*4+0][d], wvv, a0);
      a1 = fmaf(aggbuf[pg*4+1][d], wvv, a1);
      a2 = fmaf(aggbuf[pg*4+2][d], wvv, a2);
      a3 = fmaf(aggbuf[pg*4+3][d], wvv, a3);
    }
    size_t base0 = (size_t)(p0 + pg*4)*DIMF + c;
    out[base0 + 0*DIMF] = a0 + x[base0 + 0*DIMF];
    out[base0 + 1*DIMF] = a1 + x[base0 + 1*DIMF];
    out[base0 + 2*DIMF] = a2 + x[base0 + 2*DIMF];
    out[base0 + 3*DIMF] = a3 + x[base0 + 3*DIMF];
  }
}

extern "C" void kernel_launch(void* const* d_in, const int* in_sizes, int n_in,
                              void* d_out, int out_size, void* d_ws, size_t ws_size,
                              hipStream_t stream)
{
  (void)in_sizes; (void)n_in; (void)out_size; (void)ws_size;
  const float* x      = (const float*)d_in[0];
  const float* pos    = (const float*)d_in[1];
  const float* Wq     = (const float*)d_in[2];
  const float* Wk     = (const float*)d_in[3];
  const float* Wv     = (const float*)d_in[4];
  const float* mid_w1 = (const float*)d_in[5];
  const float* mid_b1 = (const float*)d_in[6];
  const float* mid_w2 = (const float*)d_in[7];
  const float* mid_b2 = (const float*)d_in[8];
  const float* pe_w1  = (const float*)d_in[9];
  const float* pe_b1  = (const float*)d_in[10];
  const float* pe_w2  = (const float*)d_in[11];
  const float* pe_b2  = (const float*)d_in[12];
  const float* fin_w  = (const float*)d_in[13];
  const float* fin_b  = (const float*)d_in[14];
  float* out = (float*)d_out;
  char* ws = (char*)d_ws;

  int*    cellcnt = (int*)   (ws + 0);         //  2 KB (512 cells)
  int*    fillp   = (int*)   (ws + 4096);      //  2 KB
  int*    starts  = (int*)   (ws + 16384);     //  2 KB
  char*   flags   = (char*)  (ws + 18432);     // 16 KB
  int*    pidx    = (int*)   (ws + 49152);     //  64 KB
  float4* pos4    = (float4*)(ws + 114688);    // 256 KB
  int*    ind     = (int*)   (ws + 376832);    //   1 MB
  short*  pw      = (short*) (ws + 1425408);   // 192 KB (6 packed 128x128 bf16 weights)
  float*  qarr    = (float*) (ws + 1622016);   //   8 MB
  float*  xkarr   = (float*) (ws + 10010624);  //   8 MB
  float*  xvarr   = (float*) (ws + 18399232);  //   8 MB  (end ~25.6 MB)

  hipMemsetAsync(cellcnt, 0, NCELL*sizeof(int), stream);
  count_kernel  <<<N_PTS/256, 256, 0, stream>>>(pos, cellcnt);
  scan_kernel   <<<1,         256, 0, stream>>>(cellcnt, starts, fillp);
  scatter_kernel<<<N_PTS/256, 256, 0, stream>>>(pos, fillp, pos4, pidx);
  knn_query64   <<<N_PTS/4,   256, 0, stream>>>(pos4, pidx, starts, cellcnt, ind, flags);
  knn_fallback  <<<N_PTS/256, 256, 0, stream>>>(pos4, pidx, starts, cellcnt, flags, ind);

  pack_all<<<dim3(64,6), 256, 0, stream>>>(Wq, Wk, Wv, pe_w2, mid_w1, mid_w2, pw);

  proj_kernel<<<N_PTS/128, 256, 0, stream>>>(x, pw, qarr, xkarr, xvarr);

  main_kernel<<<N_PTS/8, 256, 0, stream>>>(x, pos, pe_w1, pe_b1, pe_b2, mid_b1, mid_b2,
                                           fin_w, fin_b, qarr, xkarr, xvarr, ind, pw, out);
}

// Round 7
// 324.127 us; speedup vs baseline: 1.6949x; 1.0117x over previous
//
#include <hip/hip_runtime.h>
#include <hip/hip_bf16.h>

#define N_PTS 16384
#define DIMF  128
#define KNB   16
#define GRES  8
#define NCELL (GRES*GRES*GRES)

typedef __attribute__((ext_vector_type(8))) short bf16x8;
typedef __attribute__((ext_vector_type(4))) short bf16x4;
typedef __attribute__((ext_vector_type(4))) float f32x4;

__device__ __forceinline__ unsigned short f2b(float f){
  unsigned int u = __float_as_uint(f);
  u = u + 0x7fffu + ((u >> 16) & 1u);
  return (unsigned short)(u >> 16);
}
__device__ __forceinline__ float b2f(unsigned short u){
  return __uint_as_float(((unsigned)u) << 16);
}
__device__ __forceinline__ float b2fs(short s){
  return __uint_as_float(((unsigned)(unsigned short)s) << 16);
}
__device__ __forceinline__ float unsort_f(unsigned s){
  unsigned u = (s & 0x80000000u) ? (s ^ 0x80000000u) : ~s;
  return __uint_as_float(u);
}

// ---------------- KNN: grid build (GRES=8, 512 cells) ----------------
__global__ __launch_bounds__(256) void count_kernel(const float* __restrict__ pos, int* __restrict__ cnt){
  int i = blockIdx.x*256 + threadIdx.x;
  float px = pos[i*3+0], py = pos[i*3+1], pz = pos[i*3+2];
  int cx = min(GRES-1, max(0,(int)(px*(float)GRES)));
  int cy = min(GRES-1, max(0,(int)(py*(float)GRES)));
  int cz = min(GRES-1, max(0,(int)(pz*(float)GRES)));
  atomicAdd(&cnt[(cz*GRES+cy)*GRES+cx], 1);
}

__global__ __launch_bounds__(256) void scan_kernel(const int* __restrict__ cnt, int* __restrict__ starts, int* __restrict__ fillp){
  __shared__ int part[256];
  int t = threadIdx.x;
  int a = cnt[2*t], b = cnt[2*t+1];
  part[t] = a + b;
  __syncthreads();
  if (t == 0){
    int acc = 0;
    for (int i=0;i<256;++i){ int tmp = part[i]; part[i] = acc; acc += tmp; }
  }
  __syncthreads();
  int base = part[t];
  starts[2*t]   = base;     fillp[2*t]   = base;
  starts[2*t+1] = base + a; fillp[2*t+1] = base + a;
}

// sq stored numpy-style: ((x*x + y*y) + z*z), each op separately f32-rounded; also build inv: orig->slot
__global__ __launch_bounds__(256) void scatter_kernel(const float* __restrict__ pos, int* __restrict__ fillp,
                                                      float4* __restrict__ pos4, int* __restrict__ pidx,
                                                      int* __restrict__ inv){
  int i = blockIdx.x*256 + threadIdx.x;
  float px = pos[i*3+0], py = pos[i*3+1], pz = pos[i*3+2];
  int cx = min(GRES-1, max(0,(int)(px*(float)GRES)));
  int cy = min(GRES-1, max(0,(int)(py*(float)GRES)));
  int cz = min(GRES-1, max(0,(int)(pz*(float)GRES)));
  int c = (cz*GRES+cy)*GRES+cx;
  float sq = __fadd_rn(__fadd_rn(__fmul_rn(px,px), __fmul_rn(py,py)), __fmul_rn(pz,pz));
  int s = atomicAdd(&fillp[c], 1);
  pos4[s] = make_float4(px, py, pz, sq);
  pidx[s] = i;
  inv[i] = s;
}

// One wave per point. Exact top-16 by (d2, idx); d2 replicates numpy f32 bit-exactly.
// tau^2 threshold filter (exact when admitted>=16) -> ballot-compact -> 64-key bitonic.
// Output: neighbor SLOTS (via inv), in rank order (deterministic).
__global__ __launch_bounds__(256) void knn_query64(const float4* __restrict__ pos4, const int* __restrict__ pidx,
                                                   const int* __restrict__ starts, const int* __restrict__ cnt,
                                                   const int* __restrict__ inv,
                                                   int* __restrict__ ind_slot, char* __restrict__ flags){
  __shared__ unsigned long long cand[4][64];
  int lane = threadIdx.x & 63;
  int wv   = threadIdx.x >> 6;
  int t = blockIdx.x*4 + wv;
  float4 qp = pos4[t];
  float qx = qp.x, qy = qp.y, qz = qp.z, qsq = qp.w;
  int cx = min(GRES-1, max(0,(int)(qx*(float)GRES)));
  int cy = min(GRES-1, max(0,(int)(qy*(float)GRES)));
  int cz = min(GRES-1, max(0,(int)(qz*(float)GRES)));
  int zlo = max(0,cz-1), zhi = min(GRES-1,cz+1);
  int ylo = max(0,cy-1), yhi = min(GRES-1,cy+1);
  int xlo = max(0,cx-1), xhi = min(GRES-1,cx+1);

  int nb = 0;
  if (lane < 27){
    int dz = lane/9 - 1, dy = (lane/3)%3 - 1, dx = lane%3 - 1;
    int zz = cz+dz, yy = cy+dy, xx = cx+dx;
    if (zz>=zlo && zz<=zhi && yy>=ylo && yy<=yhi && xx>=xlo && xx<=xhi)
      nb = cnt[(zz*GRES+yy)*GRES+xx];
  }
  #pragma unroll
  for (int o=1;o<64;o<<=1) nb += __shfl_xor(nb, o, 64);
  float V = (float)((zhi-zlo+1)*(yhi-ylo+1)*(xhi-xlo+1)) * 0.001953125f;
  float r3 = 3.8197186f * V / (float)nb;
  float tau2 = 2.0f * __powf(r3, 0.66666667f);

  int nfound = 0;
  bool okscan = false;
  for (int it = 0; it < 8; ++it){
    nfound = 0;
    for (int zz=zlo; zz<=zhi; ++zz)
    for (int yy=ylo; yy<=yhi; ++yy)
    for (int xx=xlo; xx<=xhi; ++xx){
      int c = (zz*GRES+yy)*GRES+xx;
      int s0 = starts[c], n = cnt[c];
      for (int b = 0; b < n; b += 64){
        int o = b + lane;
        bool valid = o < n;
        float d = 3.0e38f; int idx = 0;
        if (valid){
          float4 pc = pos4[s0+o];
          idx = pidx[s0+o];
          float dot = __fmaf_rn(qz, pc.z, __fmaf_rn(qy, pc.y, __fmul_rn(qx, pc.x)));
          d   = __fsub_rn(__fadd_rn(qsq, pc.w), __fmul_rn(2.0f, dot));
        }
        bool admit = valid && (d < tau2);
        unsigned long long mask = __ballot(admit);
        if (admit){
          int pos = nfound + (int)__popcll(mask & ((1ull<<lane)-1ull));
          if (pos < 64){
            unsigned su = __float_as_uint(d);
            su ^= (unsigned)((int)su >> 31) | 0x80000000u;
            cand[wv][pos] = ((unsigned long long)su << 32) | (unsigned)idx;
          }
        }
        nfound += (int)__popcll(mask);
      }
    }
    if (nfound > 64){ tau2 *= 0.7f; continue; }
    if (nfound < 16){ tau2 *= 2.0f; continue; }
    okscan = true; break;
  }
  if (!okscan){ if (lane == 0) flags[t] = 1; return; }

  asm volatile("s_waitcnt lgkmcnt(0)" ::: "memory");
  __builtin_amdgcn_sched_barrier(0);
  unsigned long long key = (lane < nfound) ? cand[wv][lane] : ~0ull;

  #pragma unroll
  for (int k = 2; k <= 64; k <<= 1){
    #pragma unroll
    for (int j = k>>1; j >= 1; j >>= 1){
      unsigned long long other = __shfl_xor(key, j, 64);
      bool takeSmall = (((lane & k) == 0) != ((lane & j) != 0));
      bool less = other < key;
      key = (takeSmall == less) ? other : key;
    }
  }
  if (lane < 16) ind_slot[t*KNB + lane] = inv[(int)(unsigned)(key & 0xffffffffu)];

  unsigned long long k15 = __shfl(key, 15, 64);
  float b16 = unsort_f((unsigned)(k15 >> 32));
  double mg = 1.0e300;
  double dqx=(double)qx, dqy=(double)qy, dqz=(double)qz;
  const double h = 0.125;
  if (cx-1 > 0)      mg = fmin(mg, dqx - (double)(cx-1)*h);
  if (cx+1 < GRES-1) mg = fmin(mg, (double)(cx+2)*h - dqx);
  if (cy-1 > 0)      mg = fmin(mg, dqy - (double)(cy-1)*h);
  if (cy+1 < GRES-1) mg = fmin(mg, (double)(cy+2)*h - dqy);
  if (cz-1 > 0)      mg = fmin(mg, dqz - (double)(cz-1)*h);
  if (cz+1 < GRES-1) mg = fmin(mg, (double)(cz+2)*h - dqz);
  bool ok = (mg*mg > (double)b16 + 1.0e-5);
  if (lane == 0) flags[t] = ok ? 0 : 1;
}

// Exact serial fallback for flagged points; writes neighbor slots.
__global__ __launch_bounds__(256) void knn_fallback(const float4* __restrict__ pos4, const int* __restrict__ pidx,
                                                    const int* __restrict__ starts, const int* __restrict__ cnt,
                                                    const int* __restrict__ inv,
                                                    const char* __restrict__ flags, int* __restrict__ ind_slot){
  int t = blockIdx.x*256 + threadIdx.x;
  if (t >= N_PTS || !flags[t]) return;
  float4 qp = pos4[t];
  float qx = qp.x, qy = qp.y, qz = qp.z, qsq = qp.w;
  int cx = min(GRES-1, max(0,(int)(qx*(float)GRES)));
  int cy = min(GRES-1, max(0,(int)(qy*(float)GRES)));
  int cz = min(GRES-1, max(0,(int)(qz*(float)GRES)));
  float bd[KNB]; int bi[KNB];
  #pragma unroll
  for (int k=0;k<KNB;++k){ bd[k] = 3.0e38f; bi[k] = 0x7fffffff; }
  const double cinv = 0.125;
  for (int r = 0; r < GRES; ++r){
    int zlo = max(0, cz-r), zhi = min(GRES-1, cz+r);
    int ylo = max(0, cy-r), yhi = min(GRES-1, cy+r);
    int xlo = max(0, cx-r), xhi = min(GRES-1, cx+r);
    for (int zz = zlo; zz <= zhi; ++zz){
      for (int yy = ylo; yy <= yhi; ++yy){
        for (int xx = xlo; xx <= xhi; ++xx){
          int ring = max(abs(zz-cz), max(abs(yy-cy), abs(xx-cx)));
          if (ring != r) continue;
          int c = (zz*GRES+yy)*GRES+xx;
          int s0 = starts[c], e = s0 + cnt[c];
          for (int s = s0; s < e; ++s){
            float4 pc = pos4[s];
            int idx = pidx[s];
            float dot = __fmaf_rn(qz, pc.z, __fmaf_rn(qy, pc.y, __fmul_rn(qx, pc.x)));
            float d   = __fsub_rn(__fadd_rn(qsq, pc.w), __fmul_rn(2.0f, dot));
            bool adm = (d < bd[KNB-1]) || (d == bd[KNB-1] && idx < bi[KNB-1]);
            if (adm){
              #pragma unroll
              for (int p = KNB-1; p >= 1; --p){
                float pd = bd[p-1]; int pi = bi[p-1];
                bool sh  = (pd > d) || (pd == d && pi > idx);
                bool ins = (!sh) && ((bd[p] > d) || (bd[p] == d && bi[p] > idx));
                bd[p] = sh ? pd : (ins ? d   : bd[p]);
                bi[p] = sh ? pi : (ins ? idx : bi[p]);
              }
              bool s0b = (bd[0] > d) || (bd[0] == d && bi[0] > idx);
              if (s0b){ bd[0] = d; bi[0] = idx; }
            }
          }
        }
      }
    }
    if (bd[KNB-1] < 3.0e37f){
      double mg = 1.0e300;
      double dqx=(double)qx, dqy=(double)qy, dqz=(double)qz;
      if (cx - r > 0)      mg = fmin(mg, dqx - (double)(cx-r)*cinv);
      if (cx + r < GRES-1) mg = fmin(mg, (double)(cx+r+1)*cinv - dqx);
      if (cy - r > 0)      mg = fmin(mg, dqy - (double)(cy-r)*cinv);
      if (cy + r < GRES-1) mg = fmin(mg, (double)(cy+r+1)*cinv - dqy);
      if (cz - r > 0)      mg = fmin(mg, dqz - (double)(cz-r)*cinv);
      if (cz + r < GRES-1) mg = fmin(mg, (double)(cz+r+1)*cinv - dqz);
      if (mg*mg > (double)bd[KNB-1] + 1.0e-5) break;
    }
  }
  #pragma unroll
  for (int k=0;k<KNB;++k) ind_slot[t*KNB + k] = inv[bi[k]];
}

// ---------------- weight packing into B-fragment order (all 6 in one launch) ----------------
__global__ __launch_bounds__(256) void pack_all(const float* __restrict__ w0, const float* __restrict__ w1,
                                                const float* __restrict__ w2, const float* __restrict__ w3,
                                                const float* __restrict__ w4, const float* __restrict__ w5,
                                                short* __restrict__ dst){
  int slot = blockIdx.y;
  const float* src = (slot==0)?w0:(slot==1)?w1:(slot==2)?w2:(slot==3)?w3:(slot==4)?w4:w5;
  int f = blockIdx.x*256 + threadIdx.x;
  int j  = f & 7;
  int ln = (f >> 3) & 63;
  int ks = (f >> 9) & 3;
  int nt = f >> 11;
  int k = ks*32 + ((ln >> 4) << 3) + j;
  int n = nt*16 + (ln & 15);
  dst[slot*16384 + f] = (short)f2b(src[k*DIMF + n]);
}

// ---------------- proj: q/xk/xv = x@W (bf16 outputs, SLOT order) ----------------
__global__ __launch_bounds__(256) void proj_kernel(const float* __restrict__ x, const int* __restrict__ pidx,
                                                   const short* __restrict__ pw,
                                                   unsigned short* __restrict__ q, unsigned short* __restrict__ xk,
                                                   unsigned short* __restrict__ xv){
  __shared__ __align__(16) char Abuf[32768];
  int tid = threadIdx.x, lane = tid & 63, wv = tid >> 6;
  int r0 = blockIdx.x * 128;
  {
    int row = tid >> 1, half = tid & 1;
    int orig = pidx[r0 + row];
    const float4* xr = (const float4*)(x + (size_t)orig*DIMF + half*64);
    #pragma unroll
    for (int i=0;i<8;++i){
      float4 a = xr[2*i], b = xr[2*i+1];
      bf16x8 v;
      v[0]=(short)f2b(a.x); v[1]=(short)f2b(a.y); v[2]=(short)f2b(a.z); v[3]=(short)f2b(a.w);
      v[4]=(short)f2b(b.x); v[5]=(short)f2b(b.y); v[6]=(short)f2b(b.z); v[7]=(short)f2b(b.w);
      *(bf16x8*)(&Abuf[row*256 + ((half*128 + i*16) ^ ((row&7)<<4))]) = v;
    }
  }
  __syncthreads();
  #pragma unroll 1
  for (int w = 0; w < 3; ++w){
    const bf16x8* bw = (const bf16x8*)(pw + w*16384);
    unsigned short* dst = (w==0) ? q : (w==1) ? xk : xv;
    f32x4 acc[2][8];
    #pragma unroll
    for (int i=0;i<2;++i)
      #pragma unroll
      for (int nt=0;nt<8;++nt) acc[i][nt] = (f32x4){0.f,0.f,0.f,0.f};
    #pragma unroll
    for (int ks=0;ks<4;++ks){
      int ra = (wv*2)*16 + (lane&15);
      int rb = (wv*2+1)*16 + (lane&15);
      int cb = ks*64 + ((lane>>4)<<4);
      bf16x8 a0 = *(const bf16x8*)(&Abuf[ra*256 + (cb ^ ((ra&7)<<4))]);
      bf16x8 a1 = *(const bf16x8*)(&Abuf[rb*256 + (cb ^ ((rb&7)<<4))]);
      #pragma unroll
      for (int nt=0;nt<8;++nt){
        bf16x8 b = bw[(nt*4+ks)*64 + lane];
        acc[0][nt] = __builtin_amdgcn_mfma_f32_16x16x32_bf16(a0, b, acc[0][nt], 0, 0, 0);
        acc[1][nt] = __builtin_amdgcn_mfma_f32_16x16x32_bf16(a1, b, acc[1][nt], 0, 0, 0);
      }
    }
    #pragma unroll
    for (int i=0;i<2;++i){
      int mt = wv*2+i;
      #pragma unroll
      for (int nt=0;nt<8;++nt){
        #pragma unroll
        for (int r=0;r<4;++r){
          int grow = r0 + mt*16 + ((lane>>4)<<2) + r;
          dst[(size_t)grow*DIMF + nt*16 + (lane&15)] = f2b(acc[i][nt][r]);
        }
      }
    }
  }
}

// ---------------- fused main kernel: 8 sorted slots / wg ----------------
__global__ __launch_bounds__(256) void main_kernel(
    const float* __restrict__ x, const float4* __restrict__ pos4, const int* __restrict__ pidx,
    const float* __restrict__ pe_w1, const float* __restrict__ pe_b1, const float* __restrict__ pe_b2,
    const float* __restrict__ mid_b1, const float* __restrict__ mid_b2,
    const float* __restrict__ fin_w, const float* __restrict__ fin_b,
    const unsigned short* __restrict__ qarr, const unsigned short* __restrict__ xkarr,
    const unsigned short* __restrict__ xvarr,
    const int* __restrict__ ind_slot, const short* __restrict__ pw,
    float* __restrict__ out)
{
  __shared__ __align__(16) char peLDS[32768];
  __shared__ float aggbuf[8][DIMF];
  __shared__ int indbuf[128];
  __shared__ int origbuf[8];
  int tid = threadIdx.x;
  int lane = tid & 63;
  int wv = tid >> 6;
  int t0 = blockIdx.x * 8;
  if (tid < 128) indbuf[tid] = ind_slot[blockIdx.x*128 + tid];
  if (tid < 8) origbuf[tid] = pidx[t0 + tid];
  __syncthreads();

  int g = lane >> 4, kl = lane & 15;

  // Phase A: t = relu(rel @ pe_w1 + pe_b1) built directly as A-fragments (registers)
  bf16x8 tfrag[2][4];
  {
    float rx[2], ry[2], rz[2];
    #pragma unroll
    for (int i=0;i<2;++i){
      int mt = wv*2+i;
      int nbr = indbuf[mt*16 + kl];
      float4 pq = pos4[t0+mt];
      float4 pn = pos4[nbr];
      rx[i]=pq.x-pn.x; ry[i]=pq.y-pn.y; rz[i]=pq.z-pn.z;
    }
    #pragma unroll
    for (int ks=0;ks<4;++ks){
      int c0 = ks*32 + g*8;
      const float4* w0 = (const float4*)(pe_w1 + c0);
      const float4* w1 = (const float4*)(pe_w1 + DIMF + c0);
      const float4* w2 = (const float4*)(pe_w1 + 2*DIMF + c0);
      const float4* bb = (const float4*)(pe_b1 + c0);
      float4 wa0=w0[0], wa1=w0[1], wb0=w1[0], wb1=w1[1], wc0=w2[0], wc1=w2[1], wd0=bb[0], wd1=bb[1];
      float wa[8]={wa0.x,wa0.y,wa0.z,wa0.w,wa1.x,wa1.y,wa1.z,wa1.w};
      float wb[8]={wb0.x,wb0.y,wb0.z,wb0.w,wb1.x,wb1.y,wb1.z,wb1.w};
      float wc[8]={wc0.x,wc0.y,wc0.z,wc0.w,wc1.x,wc1.y,wc1.z,wc1.w};
      float wd[8]={wd0.x,wd0.y,wd0.z,wd0.w,wd1.x,wd1.y,wd1.z,wd1.w};
      #pragma unroll
      for (int i=0;i<2;++i){
        bf16x8 v;
        #pragma unroll
        for (int j=0;j<8;++j){
          float tv = fmaf(rx[i], wa[j], fmaf(ry[i], wb[j], fmaf(rz[i], wc[j], wd[j])));
          v[j] = (short)f2b(fmaxf(tv, 0.f));
        }
        tfrag[i][ks] = v;
      }
    }
  }

  f32x4 acc[2][8];

  // GEMM1: pe = t @ pe_w2 + pe_b2 (A from registers)
  {
    const bf16x8* bw = (const bf16x8*)(pw + 3*16384);
    #pragma unroll
    for (int nt=0;nt<8;++nt){
      float bv = pe_b2[nt*16 + kl];
      f32x4 iv = {bv,bv,bv,bv};
      acc[0][nt] = iv; acc[1][nt] = iv;
    }
    #pragma unroll
    for (int ks=0;ks<4;++ks){
      #pragma unroll
      for (int nt=0;nt<8;++nt){
        bf16x8 b = bw[(nt*4+ks)*64 + lane];
        acc[0][nt] = __builtin_amdgcn_mfma_f32_16x16x32_bf16(tfrag[0][ks], b, acc[0][nt], 0, 0, 0);
        acc[1][nt] = __builtin_amdgcn_mfma_f32_16x16x32_bf16(tfrag[1][ks], b, acc[1][nt], 0, 0, 0);
      }
    }
  }

  // Epilogue 1: pe -> LDS (bf16, C-layout scatter); z = xv + pe -> bf16 regs
  bf16x4 zb[2][8];
  #pragma unroll
  for (int i=0;i<2;++i){
    int mt = wv*2+i;
    int nb[4];
    #pragma unroll
    for (int r=0;r<4;++r) nb[r] = indbuf[mt*16 + g*4 + r];
    #pragma unroll
    for (int nt=0;nt<8;++nt){
      int col = nt*16 + kl;
      bf16x4 zv;
      #pragma unroll
      for (int r=0;r<4;++r){
        int row = mt*16 + g*4 + r;
        float pe = acc[i][nt][r];
        *(unsigned short*)&peLDS[row*256 + ((col*2) ^ ((row&7)<<4))] = f2b(pe);
        float xvf = b2f(xvarr[(size_t)nb[r]*DIMF + col]);
        zv[r] = (short)f2b(xvf + pe);
      }
      zb[i][nt] = zv;
    }
  }
  __syncthreads();

  // GEMM2 A-build: h = (q - xk) + pe directly as A-fragments (16B vector gathers)
  bf16x8 hfrag[2][4];
  #pragma unroll
  for (int i=0;i<2;++i){
    int mt = wv*2+i;
    int nbr = indbuf[mt*16 + kl];
    const unsigned short* qrow = qarr + (size_t)(t0+mt)*DIMF;
    const unsigned short* krow = xkarr + (size_t)nbr*DIMF;
    int row = mt*16 + kl;
    #pragma unroll
    for (int ks=0;ks<4;++ks){
      int c0 = ks*32 + g*8;
      bf16x8 q8 = *(const bf16x8*)(qrow + c0);
      bf16x8 k8 = *(const bf16x8*)(krow + c0);
      bf16x8 p8 = *(const bf16x8*)(&peLDS[row*256 + ((c0*2) ^ ((row&7)<<4))]);
      bf16x8 v;
      #pragma unroll
      for (int j=0;j<8;++j){
        float hf = (b2fs(q8[j]) - b2fs(k8[j])) + b2fs(p8[j]);
        v[j] = (short)f2b(hf);
      }
      hfrag[i][ks] = v;
    }
  }

  // GEMM2: u = relu(h @ mid_w1 + mid_b1)
  {
    const bf16x8* bw = (const bf16x8*)(pw + 4*16384);
    #pragma unroll
    for (int nt=0;nt<8;++nt){
      float bv = mid_b1[nt*16 + kl];
      f32x4 iv = {bv,bv,bv,bv};
      acc[0][nt] = iv; acc[1][nt] = iv;
    }
    #pragma unroll
    for (int ks=0;ks<4;++ks){
      #pragma unroll
      for (int nt=0;nt<8;++nt){
        bf16x8 b = bw[(nt*4+ks)*64 + lane];
        acc[0][nt] = __builtin_amdgcn_mfma_f32_16x16x32_bf16(hfrag[0][ks], b, acc[0][nt], 0, 0, 0);
        acc[1][nt] = __builtin_amdgcn_mfma_f32_16x16x32_bf16(hfrag[1][ks], b, acc[1][nt], 0, 0, 0);
      }
    }
  }
  __syncthreads();   // all pe reads done -> safe to overwrite buffer with u
  #pragma unroll
  for (int i=0;i<2;++i){
    int mt = wv*2+i;
    #pragma unroll
    for (int nt=0;nt<8;++nt){
      int col = nt*16 + kl;
      #pragma unroll
      for (int r=0;r<4;++r){
        int row = mt*16 + g*4 + r;
        *(unsigned short*)&peLDS[row*256 + ((col*2) ^ ((row&7)<<4))] = f2b(fmaxf(acc[i][nt][r], 0.f));
      }
    }
  }
  __syncthreads();

  // GEMM3: y = u @ mid_w2 + mid_b2 ; softmax over K; agg = sum(y_sm * z)
  {
    const bf16x8* bw = (const bf16x8*)(pw + 5*16384);
    #pragma unroll
    for (int nt=0;nt<8;++nt){
      float bv = mid_b2[nt*16 + kl];
      f32x4 iv = {bv,bv,bv,bv};
      acc[0][nt] = iv; acc[1][nt] = iv;
    }
    #pragma unroll
    for (int ks=0;ks<4;++ks){
      int ra = (wv*2)*16 + kl;
      int rb = (wv*2+1)*16 + kl;
      int cb = ks*64 + g*16;
      bf16x8 a0 = *(const bf16x8*)(&peLDS[ra*256 + (cb ^ ((ra&7)<<4))]);
      bf16x8 a1 = *(const bf16x8*)(&peLDS[rb*256 + (cb ^ ((rb&7)<<4))]);
      #pragma unroll
      for (int nt=0;nt<8;++nt){
        bf16x8 b = bw[(nt*4+ks)*64 + lane];
        acc[0][nt] = __builtin_amdgcn_mfma_f32_16x16x32_bf16(a0, b, acc[0][nt], 0, 0, 0);
        acc[1][nt] = __builtin_amdgcn_mfma_f32_16x16x32_bf16(a1, b, acc[1][nt], 0, 0, 0);
      }
    }
    const float invS = 0.08838834764831843f;   // 1/sqrt(128)
    #pragma unroll
    for (int i=0;i<2;++i){
      int mt = wv*2+i;
      #pragma unroll
      for (int nt=0;nt<8;++nt){
        f32x4 y = acc[i][nt];
        float mx = fmaxf(fmaxf(y[0],y[1]), fmaxf(y[2],y[3]));
        mx = fmaxf(mx, __shfl_xor(mx, 16, 64));
        mx = fmaxf(mx, __shfl_xor(mx, 32, 64));
        float e0 = __expf((y[0]-mx)*invS);
        float e1 = __expf((y[1]-mx)*invS);
        float e2 = __expf((y[2]-mx)*invS);
        float e3 = __expf((y[3]-mx)*invS);
        float ssum = e0+e1+e2+e3;
        ssum += __shfl_xor(ssum, 16, 64);
        ssum += __shfl_xor(ssum, 32, 64);
        bf16x4 zv = zb[i][nt];
        float ps = (e0*b2fs(zv[0]) + e1*b2fs(zv[1]) + e2*b2fs(zv[2]) + e3*b2fs(zv[3])) / ssum;
        ps += __shfl_xor(ps, 16, 64);
        ps += __shfl_xor(ps, 32, 64);
        if (lane < 16) aggbuf[mt][nt*16 + lane] = ps;
      }
    }
  }
  __syncthreads();

  // Final: out[orig] = agg @ fin_w + fin_b + x[orig]
  {
    int c = tid & 127;
    int pg = tid >> 7;
    float fb = fin_b[c];
    float a0 = fb, a1 = fb, a2 = fb, a3 = fb;
    for (int d = 0; d < DIMF; ++d){
      float wvv = fin_w[d*DIMF + c];
      a0 = fmaf(aggbuf[pg*4+0][d], wvv, a0);
      a1 = fmaf(aggbuf[pg*4+1][d], wvv, a1);
      a2 = fmaf(aggbuf[pg*4+2][d], wvv, a2);
      a3 = fmaf(aggbuf[pg*4+3][d], wvv, a3);
    }
    int o0 = origbuf[pg*4+0], o1 = origbuf[pg*4+1], o2 = origbuf[pg*4+2], o3 = origbuf[pg*4+3];
    out[(size_t)o0*DIMF + c] = a0 + x[(size_t)o0*DIMF + c];
    out[(size_t)o1*DIMF + c] = a1 + x[(size_t)o1*DIMF + c];
    out[(size_t)o2*DIMF + c] = a2 + x[(size_t)o2*DIMF + c];
    out[(size_t)o3*DIMF + c] = a3 + x[(size_t)o3*DIMF + c];
  }
}

extern "C" void kernel_launch(void* const* d_in, const int* in_sizes, int n_in,
                              void* d_out, int out_size, void* d_ws, size_t ws_size,
                              hipStream_t stream)
{
  (void)in_sizes; (void)n_in; (void)out_size; (void)ws_size;
  const float* x      = (const float*)d_in[0];
  const float* pos    = (const float*)d_in[1];
  const float* Wq     = (const float*)d_in[2];
  const float* Wk     = (const float*)d_in[3];
  const float* Wv     = (const float*)d_in[4];
  const float* mid_w1 = (const float*)d_in[5];
  const float* mid_b1 = (const float*)d_in[6];
  const float* mid_w2 = (const float*)d_in[7];
  const float* mid_b2 = (const float*)d_in[8];
  const float* pe_w1  = (const float*)d_in[9];
  const float* pe_b1  = (const float*)d_in[10];
  const float* pe_w2  = (const float*)d_in[11];
  const float* pe_b2  = (const float*)d_in[12];
  const float* fin_w  = (const float*)d_in[13];
  const float* fin_b  = (const float*)d_in[14];
  float* out = (float*)d_out;
  char* ws = (char*)d_ws;

  int*    cellcnt = (int*)   (ws + 0);         //  2 KB
  int*    fillp   = (int*)   (ws + 4096);      //  2 KB
  int*    starts  = (int*)   (ws + 8192);      //  2 KB
  char*   flags   = (char*)  (ws + 18432);     // 16 KB
  int*    pidx    = (int*)   (ws + 49152);     // 64 KB
  float4* pos4    = (float4*)(ws + 114688);    // 256 KB
  int*    ind     = (int*)   (ws + 376832);    //  1 MB (neighbor slots)
  short*  pw      = (short*) (ws + 1425408);   // 192 KB
  int*    inv     = (int*)   (ws + 1622016);   // 64 KB
  unsigned short* qarr  = (unsigned short*)(ws + 1687552);   // 4 MB
  unsigned short* xkarr = (unsigned short*)(ws + 5881856);   // 4 MB
  unsigned short* xvarr = (unsigned short*)(ws + 10076160);  // 4 MB (end ~14.3 MB)

  hipMemsetAsync(cellcnt, 0, NCELL*sizeof(int), stream);
  count_kernel  <<<N_PTS/256, 256, 0, stream>>>(pos, cellcnt);
  scan_kernel   <<<1,         256, 0, stream>>>(cellcnt, starts, fillp);
  scatter_kernel<<<N_PTS/256, 256, 0, stream>>>(pos, fillp, pos4, pidx, inv);
  knn_query64   <<<N_PTS/4,   256, 0, stream>>>(pos4, pidx, starts, cellcnt, inv, ind, flags);
  knn_fallback  <<<N_PTS/256, 256, 0, stream>>>(pos4, pidx, starts, cellcnt, inv, flags, ind);

  pack_all<<<dim3(64,6), 256, 0, stream>>>(Wq, Wk, Wv, pe_w2, mid_w1, mid_w2, pw);

  proj_kernel<<<N_PTS/128, 256, 0, stream>>>(x, pidx, pw, qarr, xkarr, xvarr);

  main_kernel<<<N_PTS/8, 256, 0, stream>>>(x, pos4, pidx, pe_w1, pe_b1, pe_b2, mid_b1, mid_b2,
                                           fin_w, fin_b, qarr, xkarr, xvarr, ind, pw, out);
}

// Round 8
// 322.836 us; speedup vs baseline: 1.7017x; 1.0040x over previous
//
#include <hip/hip_runtime.h>
#include <hip/hip_bf16.h>

#define N_PTS 16384
#define DIMF  128
#define KNB   16
#define GRES  8
#define NCELL (GRES*GRES*GRES)

typedef __attribute__((ext_vector_type(8))) short bf16x8;
typedef __attribute__((ext_vector_type(4))) short bf16x4;
typedef __attribute__((ext_vector_type(4))) float f32x4;

__device__ __forceinline__ unsigned short f2b(float f){
  unsigned int u = __float_as_uint(f);
  u = u + 0x7fffu + ((u >> 16) & 1u);
  return (unsigned short)(u >> 16);
}
__device__ __forceinline__ float b2f(unsigned short u){
  return __uint_as_float(((unsigned)u) << 16);
}
__device__ __forceinline__ float b2fs(short s){
  return __uint_as_float(((unsigned)(unsigned short)s) << 16);
}
__device__ __forceinline__ float unsort_f(unsigned s){
  unsigned u = (s & 0x80000000u) ? (s ^ 0x80000000u) : ~s;
  return __uint_as_float(u);
}

// ---------------- KNN: grid build (GRES=8, 512 cells) ----------------
__global__ __launch_bounds__(256) void count_kernel(const float* __restrict__ pos, int* __restrict__ cnt){
  int i = blockIdx.x*256 + threadIdx.x;
  float px = pos[i*3+0], py = pos[i*3+1], pz = pos[i*3+2];
  int cx = min(GRES-1, max(0,(int)(px*(float)GRES)));
  int cy = min(GRES-1, max(0,(int)(py*(float)GRES)));
  int cz = min(GRES-1, max(0,(int)(pz*(float)GRES)));
  atomicAdd(&cnt[(cz*GRES+cy)*GRES+cx], 1);
}

__global__ __launch_bounds__(256) void scan_kernel(const int* __restrict__ cnt, int* __restrict__ starts, int* __restrict__ fillp){
  __shared__ int part[256];
  int t = threadIdx.x;
  int a = cnt[2*t], b = cnt[2*t+1];
  part[t] = a + b;
  __syncthreads();
  if (t == 0){
    int acc = 0;
    for (int i=0;i<256;++i){ int tmp = part[i]; part[i] = acc; acc += tmp; }
  }
  __syncthreads();
  int base = part[t];
  starts[2*t]   = base;     fillp[2*t]   = base;
  starts[2*t+1] = base + a; fillp[2*t+1] = base + a;
}

// sq stored numpy-style: ((x*x + y*y) + z*z), each op separately f32-rounded; also build inv: orig->slot
__global__ __launch_bounds__(256) void scatter_kernel(const float* __restrict__ pos, int* __restrict__ fillp,
                                                      float4* __restrict__ pos4, int* __restrict__ pidx,
                                                      int* __restrict__ inv){
  int i = blockIdx.x*256 + threadIdx.x;
  float px = pos[i*3+0], py = pos[i*3+1], pz = pos[i*3+2];
  int cx = min(GRES-1, max(0,(int)(px*(float)GRES)));
  int cy = min(GRES-1, max(0,(int)(py*(float)GRES)));
  int cz = min(GRES-1, max(0,(int)(pz*(float)GRES)));
  int c = (cz*GRES+cy)*GRES+cx;
  float sq = __fadd_rn(__fadd_rn(__fmul_rn(px,px), __fmul_rn(py,py)), __fmul_rn(pz,pz));
  int s = atomicAdd(&fillp[c], 1);
  pos4[s] = make_float4(px, py, pz, sq);
  pidx[s] = i;
  inv[i] = s;
}

// One wave per point. Exact top-16 by (d2, idx); d2 replicates numpy f32 bit-exactly.
// tau^2 threshold filter (exact when admitted>=16) -> ballot-compact -> 64-key bitonic.
__global__ __launch_bounds__(256) void knn_query64(const float4* __restrict__ pos4, const int* __restrict__ pidx,
                                                   const int* __restrict__ starts, const int* __restrict__ cnt,
                                                   const int* __restrict__ inv,
                                                   int* __restrict__ ind_slot, char* __restrict__ flags){
  __shared__ unsigned long long cand[4][64];
  int lane = threadIdx.x & 63;
  int wv   = threadIdx.x >> 6;
  int t = blockIdx.x*4 + wv;
  float4 qp = pos4[t];
  float qx = qp.x, qy = qp.y, qz = qp.z, qsq = qp.w;
  int cx = min(GRES-1, max(0,(int)(qx*(float)GRES)));
  int cy = min(GRES-1, max(0,(int)(qy*(float)GRES)));
  int cz = min(GRES-1, max(0,(int)(qz*(float)GRES)));
  int zlo = max(0,cz-1), zhi = min(GRES-1,cz+1);
  int ylo = max(0,cy-1), yhi = min(GRES-1,cy+1);
  int xlo = max(0,cx-1), xhi = min(GRES-1,cx+1);

  int nb = 0;
  if (lane < 27){
    int dz = lane/9 - 1, dy = (lane/3)%3 - 1, dx = lane%3 - 1;
    int zz = cz+dz, yy = cy+dy, xx = cx+dx;
    if (zz>=zlo && zz<=zhi && yy>=ylo && yy<=yhi && xx>=xlo && xx<=xhi)
      nb = cnt[(zz*GRES+yy)*GRES+xx];
  }
  #pragma unroll
  for (int o=1;o<64;o<<=1) nb += __shfl_xor(nb, o, 64);
  float V = (float)((zhi-zlo+1)*(yhi-ylo+1)*(xhi-xlo+1)) * 0.001953125f;
  float r3 = 3.8197186f * V / (float)nb;
  float tau2 = 2.0f * __powf(r3, 0.66666667f);

  int nfound = 0;
  bool okscan = false;
  for (int it = 0; it < 8; ++it){
    nfound = 0;
    for (int zz=zlo; zz<=zhi; ++zz)
    for (int yy=ylo; yy<=yhi; ++yy)
    for (int xx=xlo; xx<=xhi; ++xx){
      int c = (zz*GRES+yy)*GRES+xx;
      int s0 = starts[c], n = cnt[c];
      for (int b = 0; b < n; b += 64){
        int o = b + lane;
        bool valid = o < n;
        float d = 3.0e38f; int idx = 0;
        if (valid){
          float4 pc = pos4[s0+o];
          idx = pidx[s0+o];
          float dot = __fmaf_rn(qz, pc.z, __fmaf_rn(qy, pc.y, __fmul_rn(qx, pc.x)));
          d   = __fsub_rn(__fadd_rn(qsq, pc.w), __fmul_rn(2.0f, dot));
        }
        bool admit = valid && (d < tau2);
        unsigned long long mask = __ballot(admit);
        if (admit){
          int pos = nfound + (int)__popcll(mask & ((1ull<<lane)-1ull));
          if (pos < 64){
            unsigned su = __float_as_uint(d);
            su ^= (unsigned)((int)su >> 31) | 0x80000000u;
            cand[wv][pos] = ((unsigned long long)su << 32) | (unsigned)idx;
          }
        }
        nfound += (int)__popcll(mask);
      }
    }
    if (nfound > 64){ tau2 *= 0.7f; continue; }
    if (nfound < 16){ tau2 *= 2.0f; continue; }
    okscan = true; break;
  }
  if (!okscan){ if (lane == 0) flags[t] = 1; return; }

  asm volatile("s_waitcnt lgkmcnt(0)" ::: "memory");
  __builtin_amdgcn_sched_barrier(0);
  unsigned long long key = (lane < nfound) ? cand[wv][lane] : ~0ull;

  #pragma unroll
  for (int k = 2; k <= 64; k <<= 1){
    #pragma unroll
    for (int j = k>>1; j >= 1; j >>= 1){
      unsigned long long other = __shfl_xor(key, j, 64);
      bool takeSmall = (((lane & k) == 0) != ((lane & j) != 0));
      bool less = other < key;
      key = (takeSmall == less) ? other : key;
    }
  }
  if (lane < 16) ind_slot[t*KNB + lane] = inv[(int)(unsigned)(key & 0xffffffffu)];

  unsigned long long k15 = __shfl(key, 15, 64);
  float b16 = unsort_f((unsigned)(k15 >> 32));
  double mg = 1.0e300;
  double dqx=(double)qx, dqy=(double)qy, dqz=(double)qz;
  const double h = 0.125;
  if (cx-1 > 0)      mg = fmin(mg, dqx - (double)(cx-1)*h);
  if (cx+1 < GRES-1) mg = fmin(mg, (double)(cx+2)*h - dqx);
  if (cy-1 > 0)      mg = fmin(mg, dqy - (double)(cy-1)*h);
  if (cy+1 < GRES-1) mg = fmin(mg, (double)(cy+2)*h - dqy);
  if (cz-1 > 0)      mg = fmin(mg, dqz - (double)(cz-1)*h);
  if (cz+1 < GRES-1) mg = fmin(mg, (double)(cz+2)*h - dqz);
  bool ok = (mg*mg > (double)b16 + 1.0e-5);
  if (lane == 0) flags[t] = ok ? 0 : 1;
}

// Exact serial fallback for flagged points; writes neighbor slots.
__global__ __launch_bounds__(256) void knn_fallback(const float4* __restrict__ pos4, const int* __restrict__ pidx,
                                                    const int* __restrict__ starts, const int* __restrict__ cnt,
                                                    const int* __restrict__ inv,
                                                    const char* __restrict__ flags, int* __restrict__ ind_slot){
  int t = blockIdx.x*256 + threadIdx.x;
  if (t >= N_PTS || !flags[t]) return;
  float4 qp = pos4[t];
  float qx = qp.x, qy = qp.y, qz = qp.z, qsq = qp.w;
  int cx = min(GRES-1, max(0,(int)(qx*(float)GRES)));
  int cy = min(GRES-1, max(0,(int)(qy*(float)GRES)));
  int cz = min(GRES-1, max(0,(int)(qz*(float)GRES)));
  float bd[KNB]; int bi[KNB];
  #pragma unroll
  for (int k=0;k<KNB;++k){ bd[k] = 3.0e38f; bi[k] = 0x7fffffff; }
  const double cinv = 0.125;
  for (int r = 0; r < GRES; ++r){
    int zlo = max(0, cz-r), zhi = min(GRES-1, cz+r);
    int ylo = max(0, cy-r), yhi = min(GRES-1, cy+r);
    int xlo = max(0, cx-r), xhi = min(GRES-1, cx+r);
    for (int zz = zlo; zz <= zhi; ++zz){
      for (int yy = ylo; yy <= yhi; ++yy){
        for (int xx = xlo; xx <= xhi; ++xx){
          int ring = max(abs(zz-cz), max(abs(yy-cy), abs(xx-cx)));
          if (ring != r) continue;
          int c = (zz*GRES+yy)*GRES+xx;
          int s0 = starts[c], e = s0 + cnt[c];
          for (int s = s0; s < e; ++s){
            float4 pc = pos4[s];
            int idx = pidx[s];
            float dot = __fmaf_rn(qz, pc.z, __fmaf_rn(qy, pc.y, __fmul_rn(qx, pc.x)));
            float d   = __fsub_rn(__fadd_rn(qsq, pc.w), __fmul_rn(2.0f, dot));
            bool adm = (d < bd[KNB-1]) || (d == bd[KNB-1] && idx < bi[KNB-1]);
            if (adm){
              #pragma unroll
              for (int p = KNB-1; p >= 1; --p){
                float pd = bd[p-1]; int pi = bi[p-1];
                bool sh  = (pd > d) || (pd == d && pi > idx);
                bool ins = (!sh) && ((bd[p] > d) || (bd[p] == d && bi[p] > idx));
                bd[p] = sh ? pd : (ins ? d   : bd[p]);
                bi[p] = sh ? pi : (ins ? idx : bi[p]);
              }
              bool s0b = (bd[0] > d) || (bd[0] == d && bi[0] > idx);
              if (s0b){ bd[0] = d; bi[0] = idx; }
            }
          }
        }
      }
    }
    if (bd[KNB-1] < 3.0e37f){
      double mg = 1.0e300;
      double dqx=(double)qx, dqy=(double)qy, dqz=(double)qz;
      if (cx - r > 0)      mg = fmin(mg, dqx - (double)(cx-r)*cinv);
      if (cx + r < GRES-1) mg = fmin(mg, (double)(cx+r+1)*cinv - dqx);
      if (cy - r > 0)      mg = fmin(mg, dqy - (double)(cy-r)*cinv);
      if (cy + r < GRES-1) mg = fmin(mg, (double)(cy+r+1)*cinv - dqy);
      if (cz - r > 0)      mg = fmin(mg, dqz - (double)(cz-r)*cinv);
      if (cz + r < GRES-1) mg = fmin(mg, (double)(cz+r+1)*cinv - dqz);
      if (mg*mg > (double)bd[KNB-1] + 1.0e-5) break;
    }
  }
  #pragma unroll
  for (int k=0;k<KNB;++k) ind_slot[t*KNB + k] = inv[bi[k]];
}

// ---------------- weight packing into B-fragment order (7 weights, one launch) ----------------
__global__ __launch_bounds__(256) void pack_all(const float* __restrict__ w0, const float* __restrict__ w1,
                                                const float* __restrict__ w2, const float* __restrict__ w3,
                                                const float* __restrict__ w4, const float* __restrict__ w5,
                                                const float* __restrict__ w6,
                                                short* __restrict__ dst){
  int slot = blockIdx.y;
  const float* src = (slot==0)?w0:(slot==1)?w1:(slot==2)?w2:(slot==3)?w3:(slot==4)?w4:(slot==5)?w5:w6;
  int f = blockIdx.x*256 + threadIdx.x;
  int j  = f & 7;
  int ln = (f >> 3) & 63;
  int ks = (f >> 9) & 3;
  int nt = f >> 11;
  int k = ks*32 + ((ln >> 4) << 3) + j;
  int n = nt*16 + (ln & 15);
  dst[slot*16384 + f] = (short)f2b(src[k*DIMF + n]);
}

// ---------------- proj: q/xk/xv = x@W (bf16 outputs, SLOT order) ----------------
__global__ __launch_bounds__(256) void proj_kernel(const float* __restrict__ x, const int* __restrict__ pidx,
                                                   const short* __restrict__ pw,
                                                   unsigned short* __restrict__ q, unsigned short* __restrict__ xk,
                                                   unsigned short* __restrict__ xv){
  __shared__ __align__(16) char Abuf[32768];
  int tid = threadIdx.x, lane = tid & 63, wv = tid >> 6;
  int r0 = blockIdx.x * 128;
  {
    int row = tid >> 1, half = tid & 1;
    int orig = pidx[r0 + row];
    const float4* xr = (const float4*)(x + (size_t)orig*DIMF + half*64);
    #pragma unroll
    for (int i=0;i<8;++i){
      float4 a = xr[2*i], b = xr[2*i+1];
      bf16x8 v;
      v[0]=(short)f2b(a.x); v[1]=(short)f2b(a.y); v[2]=(short)f2b(a.z); v[3]=(short)f2b(a.w);
      v[4]=(short)f2b(b.x); v[5]=(short)f2b(b.y); v[6]=(short)f2b(b.z); v[7]=(short)f2b(b.w);
      *(bf16x8*)(&Abuf[row*256 + ((half*128 + i*16) ^ ((row&7)<<4))]) = v;
    }
  }
  __syncthreads();
  #pragma unroll 1
  for (int w = 0; w < 3; ++w){
    const bf16x8* bw = (const bf16x8*)(pw + w*16384);
    unsigned short* dst = (w==0) ? q : (w==1) ? xk : xv;
    f32x4 acc[2][8];
    #pragma unroll
    for (int i=0;i<2;++i)
      #pragma unroll
      for (int nt=0;nt<8;++nt) acc[i][nt] = (f32x4){0.f,0.f,0.f,0.f};
    #pragma unroll
    for (int ks=0;ks<4;++ks){
      int ra = (wv*2)*16 + (lane&15);
      int rb = (wv*2+1)*16 + (lane&15);
      int cb = ks*64 + ((lane>>4)<<4);
      bf16x8 a0 = *(const bf16x8*)(&Abuf[ra*256 + (cb ^ ((ra&7)<<4))]);
      bf16x8 a1 = *(const bf16x8*)(&Abuf[rb*256 + (cb ^ ((rb&7)<<4))]);
      #pragma unroll
      for (int nt=0;nt<8;++nt){
        bf16x8 b = bw[(nt*4+ks)*64 + lane];
        acc[0][nt] = __builtin_amdgcn_mfma_f32_16x16x32_bf16(a0, b, acc[0][nt], 0, 0, 0);
        acc[1][nt] = __builtin_amdgcn_mfma_f32_16x16x32_bf16(a1, b, acc[1][nt], 0, 0, 0);
      }
    }
    #pragma unroll
    for (int i=0;i<2;++i){
      int mt = wv*2+i;
      #pragma unroll
      for (int nt=0;nt<8;++nt){
        #pragma unroll
        for (int r=0;r<4;++r){
          int grow = r0 + mt*16 + ((lane>>4)<<2) + r;
          dst[(size_t)grow*DIMF + nt*16 + (lane&15)] = f2b(acc[i][nt][r]);
        }
      }
    }
  }
}

// ---------------- fused main kernel: 8 sorted slots / wg, 8 waves, 1 m-tile/wave ----------------
__global__ __launch_bounds__(512, 4) void main_kernel(
    const float* __restrict__ x, const float4* __restrict__ pos4, const int* __restrict__ pidx,
    const float* __restrict__ pe_w1, const float* __restrict__ pe_b1, const float* __restrict__ pe_b2,
    const float* __restrict__ mid_b1, const float* __restrict__ mid_b2, const float* __restrict__ fin_b,
    const unsigned short* __restrict__ qarr, const unsigned short* __restrict__ xkarr,
    const unsigned short* __restrict__ xvarr,
    const int* __restrict__ ind_slot, const short* __restrict__ pw,
    float* __restrict__ out)
{
  __shared__ __align__(16) char peLDS[32768];
  __shared__ float aggT[DIMF][8];     // transposed agg: [col][point]
  __shared__ int indbuf[128];
  __shared__ int origbuf[8];
  int tid = threadIdx.x;
  int lane = tid & 63;
  int wv = tid >> 6;                  // 0..7, owns m-tile mt = wv
  int t0 = blockIdx.x * 8;
  if (tid < 128) indbuf[tid] = ind_slot[blockIdx.x*128 + tid];
  if (tid < 8) origbuf[tid] = pidx[t0 + tid];
  __syncthreads();

  int g = lane >> 4, kl = lane & 15;
  int mt = wv;

  // ---- early-issue z gathers (latency hides under tfrag build + GEMM1) ----
  int nb4[4];
  #pragma unroll
  for (int r=0;r<4;++r) nb4[r] = indbuf[mt*16 + g*4 + r];
  unsigned short zraw[8][4];
  #pragma unroll
  for (int nt=0;nt<8;++nt)
    #pragma unroll
    for (int r=0;r<4;++r)
      zraw[nt][r] = xvarr[(size_t)nb4[r]*DIMF + nt*16 + kl];

  // ---- Phase A: t = relu(rel @ pe_w1 + pe_b1) directly as A-fragments ----
  int nbr = indbuf[mt*16 + kl];
  bf16x8 tfrag[4];
  {
    float4 pq = pos4[t0+mt];
    float4 pn = pos4[nbr];
    float rx = pq.x-pn.x, ry = pq.y-pn.y, rz = pq.z-pn.z;
    #pragma unroll
    for (int ks=0;ks<4;++ks){
      int c0 = ks*32 + g*8;
      const float4* w0 = (const float4*)(pe_w1 + c0);
      const float4* w1 = (const float4*)(pe_w1 + DIMF + c0);
      const float4* w2 = (const float4*)(pe_w1 + 2*DIMF + c0);
      const float4* bb = (const float4*)(pe_b1 + c0);
      float4 wa0=w0[0], wa1=w0[1], wb0=w1[0], wb1=w1[1], wc0=w2[0], wc1=w2[1], wd0=bb[0], wd1=bb[1];
      float wa[8]={wa0.x,wa0.y,wa0.z,wa0.w,wa1.x,wa1.y,wa1.z,wa1.w};
      float wb[8]={wb0.x,wb0.y,wb0.z,wb0.w,wb1.x,wb1.y,wb1.z,wb1.w};
      float wc[8]={wc0.x,wc0.y,wc0.z,wc0.w,wc1.x,wc1.y,wc1.z,wc1.w};
      float wd[8]={wd0.x,wd0.y,wd0.z,wd0.w,wd1.x,wd1.y,wd1.z,wd1.w};
      bf16x8 v;
      #pragma unroll
      for (int j=0;j<8;++j){
        float tv = fmaf(rx, wa[j], fmaf(ry, wb[j], fmaf(rz, wc[j], wd[j])));
        v[j] = (short)f2b(fmaxf(tv, 0.f));
      }
      tfrag[ks] = v;
    }
  }

  f32x4 acc[8];

  // ---- GEMM1: pe = t @ pe_w2 + pe_b2 ----
  {
    const bf16x8* bw = (const bf16x8*)(pw + 3*16384);
    #pragma unroll
    for (int nt=0;nt<8;++nt){
      float bv = pe_b2[nt*16 + kl];
      acc[nt] = (f32x4){bv,bv,bv,bv};
    }
    #pragma unroll
    for (int ks=0;ks<4;++ks){
      #pragma unroll
      for (int nt=0;nt<8;++nt){
        bf16x8 b = bw[(nt*4+ks)*64 + lane];
        acc[nt] = __builtin_amdgcn_mfma_f32_16x16x32_bf16(tfrag[ks], b, acc[nt], 0, 0, 0);
      }
    }
  }

  // ---- Epilogue 1: pe -> LDS (bf16, swizzled); z = xv + pe -> bf16 regs ----
  bf16x4 zb[8];
  #pragma unroll
  for (int nt=0;nt<8;++nt){
    int col = nt*16 + kl;
    bf16x4 zv;
    #pragma unroll
    for (int r=0;r<4;++r){
      int row = mt*16 + g*4 + r;
      float pe = acc[nt][r];
      *(unsigned short*)&peLDS[row*256 + ((col*2) ^ ((row&7)<<4))] = f2b(pe);
      zv[r] = (short)f2b(b2f(zraw[nt][r]) + pe);
    }
    zb[nt] = zv;
  }

  // prefetch q/k A-layout vector gathers (fly across the barrier drain)
  bf16x8 q8[4], k8[4];
  {
    const unsigned short* qrow = qarr + (size_t)(t0+mt)*DIMF;
    const unsigned short* krow = xkarr + (size_t)nbr*DIMF;
    #pragma unroll
    for (int ks=0;ks<4;++ks){
      int c0 = ks*32 + g*8;
      q8[ks] = *(const bf16x8*)(qrow + c0);
      k8[ks] = *(const bf16x8*)(krow + c0);
    }
  }
  __syncthreads();

  // ---- GEMM2 A-build: h = (q - xk) + pe ----
  bf16x8 hfrag[4];
  {
    int row = mt*16 + kl;
    #pragma unroll
    for (int ks=0;ks<4;++ks){
      int c0 = ks*32 + g*8;
      bf16x8 p8 = *(const bf16x8*)(&peLDS[row*256 + ((c0*2) ^ ((row&7)<<4))]);
      bf16x8 v;
      #pragma unroll
      for (int j=0;j<8;++j){
        float hf = (b2fs(q8[ks][j]) - b2fs(k8[ks][j])) + b2fs(p8[j]);
        v[j] = (short)f2b(hf);
      }
      hfrag[ks] = v;
    }
  }

  // ---- GEMM2: u = relu(h @ mid_w1 + mid_b1) ----
  {
    const bf16x8* bw = (const bf16x8*)(pw + 4*16384);
    #pragma unroll
    for (int nt=0;nt<8;++nt){
      float bv = mid_b1[nt*16 + kl];
      acc[nt] = (f32x4){bv,bv,bv,bv};
    }
    #pragma unroll
    for (int ks=0;ks<4;++ks){
      #pragma unroll
      for (int nt=0;nt<8;++nt){
        bf16x8 b = bw[(nt*4+ks)*64 + lane];
        acc[nt] = __builtin_amdgcn_mfma_f32_16x16x32_bf16(hfrag[ks], b, acc[nt], 0, 0, 0);
      }
    }
  }
  __syncthreads();   // all pe reads done -> safe to overwrite with u
  #pragma unroll
  for (int nt=0;nt<8;++nt){
    int col = nt*16 + kl;
    #pragma unroll
    for (int r=0;r<4;++r){
      int row = mt*16 + g*4 + r;
      *(unsigned short*)&peLDS[row*256 + ((col*2) ^ ((row&7)<<4))] = f2b(fmaxf(acc[nt][r], 0.f));
    }
  }
  __syncthreads();

  // ---- GEMM3: y = u @ mid_w2 + mid_b2 ; softmax over K; agg -> aggT ----
  {
    const bf16x8* bw = (const bf16x8*)(pw + 5*16384);
    #pragma unroll
    for (int nt=0;nt<8;++nt){
      float bv = mid_b2[nt*16 + kl];
      acc[nt] = (f32x4){bv,bv,bv,bv};
    }
    #pragma unroll
    for (int ks=0;ks<4;++ks){
      int ra = mt*16 + kl;
      int cb = ks*64 + g*16;
      bf16x8 a0 = *(const bf16x8*)(&peLDS[ra*256 + (cb ^ ((ra&7)<<4))]);
      #pragma unroll
      for (int nt=0;nt<8;++nt){
        bf16x8 b = bw[(nt*4+ks)*64 + lane];
        acc[nt] = __builtin_amdgcn_mfma_f32_16x16x32_bf16(a0, b, acc[nt], 0, 0, 0);
      }
    }
    const float invS = 0.08838834764831843f;   // 1/sqrt(128)
    #pragma unroll
    for (int nt=0;nt<8;++nt){
      f32x4 y = acc[nt];
      float mx = fmaxf(fmaxf(y[0],y[1]), fmaxf(y[2],y[3]));
      mx = fmaxf(mx, __shfl_xor(mx, 16, 64));
      mx = fmaxf(mx, __shfl_xor(mx, 32, 64));
      float e0 = __expf((y[0]-mx)*invS);
      float e1 = __expf((y[1]-mx)*invS);
      float e2 = __expf((y[2]-mx)*invS);
      float e3 = __expf((y[3]-mx)*invS);
      float ssum = e0+e1+e2+e3;
      ssum += __shfl_xor(ssum, 16, 64);
      ssum += __shfl_xor(ssum, 32, 64);
      bf16x4 zv = zb[nt];
      float ps = (e0*b2fs(zv[0]) + e1*b2fs(zv[1]) + e2*b2fs(zv[2]) + e3*b2fs(zv[3])) / ssum;
      ps += __shfl_xor(ps, 16, 64);
      ps += __shfl_xor(ps, 32, 64);
      if (lane < 16) aggT[nt*16 + lane][mt] = ps;
    }
  }
  __syncthreads();

  // ---- Final via MFMA: out = agg @ fin_w + fin_b + x ; wave wv owns N-tile nt=wv ----
  {
    const bf16x8* bwf = (const bf16x8*)(pw + 6*16384);
    f32x4 facc = (f32x4){0.f,0.f,0.f,0.f};
    #pragma unroll
    for (int ks=0;ks<4;++ks){
      int c0 = ks*32 + g*8;
      bf16x8 a;
      #pragma unroll
      for (int j=0;j<8;++j)
        a[j] = (kl < 8) ? (short)f2b(aggT[c0+j][kl]) : (short)0;
      bf16x8 b = bwf[(wv*4+ks)*64 + lane];
      facc = __builtin_amdgcn_mfma_f32_16x16x32_bf16(a, b, facc, 0, 0, 0);
    }
    int col = wv*16 + kl;
    float fb = fin_b[col];
    if (g < 2){
      #pragma unroll
      for (int r=0;r<4;++r){
        int prow = g*4 + r;
        int o = origbuf[prow];
        out[(size_t)o*DIMF + col] = facc[r] + fb + x[(size_t)o*DIMF + col];
      }
    }
  }
}

extern "C" void kernel_launch(void* const* d_in, const int* in_sizes, int n_in,
                              void* d_out, int out_size, void* d_ws, size_t ws_size,
                              hipStream_t stream)
{
  (void)in_sizes; (void)n_in; (void)out_size; (void)ws_size;
  const float* x      = (const float*)d_in[0];
  const float* pos    = (const float*)d_in[1];
  const float* Wq     = (const float*)d_in[2];
  const float* Wk     = (const float*)d_in[3];
  const float* Wv     = (const float*)d_in[4];
  const float* mid_w1 = (const float*)d_in[5];
  const float* mid_b1 = (const float*)d_in[6];
  const float* mid_w2 = (const float*)d_in[7];
  const float* mid_b2 = (const float*)d_in[8];
  const float* pe_w1  = (const float*)d_in[9];
  const float* pe_b1  = (const float*)d_in[10];
  const float* pe_w2  = (const float*)d_in[11];
  const float* pe_b2  = (const float*)d_in[12];
  const float* fin_w  = (const float*)d_in[13];
  const float* fin_b  = (const float*)d_in[14];
  float* out = (float*)d_out;
  char* ws = (char*)d_ws;

  int*    cellcnt = (int*)   (ws + 0);         //  2 KB
  int*    fillp   = (int*)   (ws + 4096);      //  2 KB
  int*    starts  = (int*)   (ws + 8192);      //  2 KB
  char*   flags   = (char*)  (ws + 18432);     // 16 KB
  int*    pidx    = (int*)   (ws + 49152);     // 64 KB
  float4* pos4    = (float4*)(ws + 114688);    // 256 KB
  int*    ind     = (int*)   (ws + 376832);    //  1 MB (neighbor slots)
  short*  pw      = (short*) (ws + 1425408);   // 224 KB (7 packed 128x128 bf16 weights)
  int*    inv     = (int*)   (ws + 1654784);   // 64 KB
  unsigned short* qarr  = (unsigned short*)(ws + 1720320);   // 4 MB
  unsigned short* xkarr = (unsigned short*)(ws + 5914624);   // 4 MB
  unsigned short* xvarr = (unsigned short*)(ws + 10108928);  // 4 MB (end ~14.3 MB)

  hipMemsetAsync(cellcnt, 0, NCELL*sizeof(int), stream);
  count_kernel  <<<N_PTS/256, 256, 0, stream>>>(pos, cellcnt);
  scan_kernel   <<<1,         256, 0, stream>>>(cellcnt, starts, fillp);
  scatter_kernel<<<N_PTS/256, 256, 0, stream>>>(pos, fillp, pos4, pidx, inv);
  knn_query64   <<<N_PTS/4,   256, 0, stream>>>(pos4, pidx, starts, cellcnt, inv, ind, flags);
  knn_fallback  <<<N_PTS/256, 256, 0, stream>>>(pos4, pidx, starts, cellcnt, inv, flags, ind);

  pack_all<<<dim3(64,7), 256, 0, stream>>>(Wq, Wk, Wv, pe_w2, mid_w1, mid_w2, fin_w, pw);

  proj_kernel<<<N_PTS/128, 256, 0, stream>>>(x, pidx, pw, qarr, xkarr, xvarr);

  main_kernel<<<N_PTS/8, 512, 0, stream>>>(x, pos4, pidx, pe_w1, pe_b1, pe_b2, mid_b1, mid_b2, fin_b,
                                           qarr, xkarr, xvarr, ind, pw, out);
}

// Round 9
// 239.944 us; speedup vs baseline: 2.2895x; 1.3455x over previous
//
#include <hip/hip_runtime.h>
#include <hip/hip_bf16.h>

#define N_PTS 16384
#define DIMF  128
#define KNB   16
#define GRES  8
#define NCELL (GRES*GRES*GRES)

typedef __attribute__((ext_vector_type(8))) short bf16x8;
typedef __attribute__((ext_vector_type(4))) short bf16x4;
typedef __attribute__((ext_vector_type(4))) float f32x4;

__device__ __forceinline__ unsigned short f2b(float f){
  unsigned int u = __float_as_uint(f);
  u = u + 0x7fffu + ((u >> 16) & 1u);
  return (unsigned short)(u >> 16);
}
__device__ __forceinline__ float b2f(unsigned short u){
  return __uint_as_float(((unsigned)u) << 16);
}
__device__ __forceinline__ float b2fs(short s){
  return __uint_as_float(((unsigned)(unsigned short)s) << 16);
}
__device__ __forceinline__ float unsort_f(unsigned s){
  unsigned u = (s & 0x80000000u) ? (s ^ 0x80000000u) : ~s;
  return __uint_as_float(u);
}

// ---------------- KNN: grid build (GRES=8, 512 cells) ----------------
__global__ __launch_bounds__(256) void count_kernel(const float* __restrict__ pos, int* __restrict__ cnt){
  int i = blockIdx.x*256 + threadIdx.x;
  float px = pos[i*3+0], py = pos[i*3+1], pz = pos[i*3+2];
  int cx = min(GRES-1, max(0,(int)(px*(float)GRES)));
  int cy = min(GRES-1, max(0,(int)(py*(float)GRES)));
  int cz = min(GRES-1, max(0,(int)(pz*(float)GRES)));
  atomicAdd(&cnt[(cz*GRES+cy)*GRES+cx], 1);
}

__global__ __launch_bounds__(256) void scan_kernel(const int* __restrict__ cnt, int* __restrict__ starts, int* __restrict__ fillp){
  __shared__ int part[256];
  int t = threadIdx.x;
  int a = cnt[2*t], b = cnt[2*t+1];
  part[t] = a + b;
  __syncthreads();
  if (t == 0){
    int acc = 0;
    for (int i=0;i<256;++i){ int tmp = part[i]; part[i] = acc; acc += tmp; }
  }
  __syncthreads();
  int base = part[t];
  starts[2*t]   = base;     fillp[2*t]   = base;
  starts[2*t+1] = base + a; fillp[2*t+1] = base + a;
}

// sq stored numpy-style: ((x*x + y*y) + z*z), each op separately f32-rounded; also build inv: orig->slot
__global__ __launch_bounds__(256) void scatter_kernel(const float* __restrict__ pos, int* __restrict__ fillp,
                                                      float4* __restrict__ pos4, int* __restrict__ pidx,
                                                      int* __restrict__ inv){
  int i = blockIdx.x*256 + threadIdx.x;
  float px = pos[i*3+0], py = pos[i*3+1], pz = pos[i*3+2];
  int cx = min(GRES-1, max(0,(int)(px*(float)GRES)));
  int cy = min(GRES-1, max(0,(int)(py*(float)GRES)));
  int cz = min(GRES-1, max(0,(int)(pz*(float)GRES)));
  int c = (cz*GRES+cy)*GRES+cx;
  float sq = __fadd_rn(__fadd_rn(__fmul_rn(px,px), __fmul_rn(py,py)), __fmul_rn(pz,pz));
  int s = atomicAdd(&fillp[c], 1);
  pos4[s] = make_float4(px, py, pz, sq);
  pidx[s] = i;
  inv[i] = s;
}

// One wave per point. Exact top-16 by (d2, idx); d2 replicates numpy f32 bit-exactly.
// tau^2 threshold filter (exact when admitted>=16) -> ballot-compact -> 64-key bitonic.
__global__ __launch_bounds__(256) void knn_query64(const float4* __restrict__ pos4, const int* __restrict__ pidx,
                                                   const int* __restrict__ starts, const int* __restrict__ cnt,
                                                   const int* __restrict__ inv,
                                                   int* __restrict__ ind_slot, char* __restrict__ flags){
  __shared__ unsigned long long cand[4][64];
  int lane = threadIdx.x & 63;
  int wv   = threadIdx.x >> 6;
  int t = blockIdx.x*4 + wv;
  float4 qp = pos4[t];
  float qx = qp.x, qy = qp.y, qz = qp.z, qsq = qp.w;
  int cx = min(GRES-1, max(0,(int)(qx*(float)GRES)));
  int cy = min(GRES-1, max(0,(int)(qy*(float)GRES)));
  int cz = min(GRES-1, max(0,(int)(qz*(float)GRES)));
  int zlo = max(0,cz-1), zhi = min(GRES-1,cz+1);
  int ylo = max(0,cy-1), yhi = min(GRES-1,cy+1);
  int xlo = max(0,cx-1), xhi = min(GRES-1,cx+1);

  int nb = 0;
  if (lane < 27){
    int dz = lane/9 - 1, dy = (lane/3)%3 - 1, dx = lane%3 - 1;
    int zz = cz+dz, yy = cy+dy, xx = cx+dx;
    if (zz>=zlo && zz<=zhi && yy>=ylo && yy<=yhi && xx>=xlo && xx<=xhi)
      nb = cnt[(zz*GRES+yy)*GRES+xx];
  }
  #pragma unroll
  for (int o=1;o<64;o<<=1) nb += __shfl_xor(nb, o, 64);
  float V = (float)((zhi-zlo+1)*(yhi-ylo+1)*(xhi-xlo+1)) * 0.001953125f;
  float r3 = 3.8197186f * V / (float)nb;
  float tau2 = 2.0f * __powf(r3, 0.66666667f);

  int nfound = 0;
  bool okscan = false;
  for (int it = 0; it < 8; ++it){
    nfound = 0;
    for (int zz=zlo; zz<=zhi; ++zz)
    for (int yy=ylo; yy<=yhi; ++yy)
    for (int xx=xlo; xx<=xhi; ++xx){
      int c = (zz*GRES+yy)*GRES+xx;
      int s0 = starts[c], n = cnt[c];
      for (int b = 0; b < n; b += 64){
        int o = b + lane;
        bool valid = o < n;
        float d = 3.0e38f; int idx = 0;
        if (valid){
          float4 pc = pos4[s0+o];
          idx = pidx[s0+o];
          float dot = __fmaf_rn(qz, pc.z, __fmaf_rn(qy, pc.y, __fmul_rn(qx, pc.x)));
          d   = __fsub_rn(__fadd_rn(qsq, pc.w), __fmul_rn(2.0f, dot));
        }
        bool admit = valid && (d < tau2);
        unsigned long long mask = __ballot(admit);
        if (admit){
          int pos = nfound + (int)__popcll(mask & ((1ull<<lane)-1ull));
          if (pos < 64){
            unsigned su = __float_as_uint(d);
            su ^= (unsigned)((int)su >> 31) | 0x80000000u;
            cand[wv][pos] = ((unsigned long long)su << 32) | (unsigned)idx;
          }
        }
        nfound += (int)__popcll(mask);
      }
    }
    if (nfound > 64){ tau2 *= 0.7f; continue; }
    if (nfound < 16){ tau2 *= 2.0f; continue; }
    okscan = true; break;
  }
  if (!okscan){ if (lane == 0) flags[t] = 1; return; }

  asm volatile("s_waitcnt lgkmcnt(0)" ::: "memory");
  __builtin_amdgcn_sched_barrier(0);
  unsigned long long key = (lane < nfound) ? cand[wv][lane] : ~0ull;

  #pragma unroll
  for (int k = 2; k <= 64; k <<= 1){
    #pragma unroll
    for (int j = k>>1; j >= 1; j >>= 1){
      unsigned long long other = __shfl_xor(key, j, 64);
      bool takeSmall = (((lane & k) == 0) != ((lane & j) != 0));
      bool less = other < key;
      key = (takeSmall == less) ? other : key;
    }
  }
  if (lane < 16) ind_slot[t*KNB + lane] = inv[(int)(unsigned)(key & 0xffffffffu)];

  unsigned long long k15 = __shfl(key, 15, 64);
  float b16 = unsort_f((unsigned)(k15 >> 32));
  double mg = 1.0e300;
  double dqx=(double)qx, dqy=(double)qy, dqz=(double)qz;
  const double h = 0.125;
  if (cx-1 > 0)      mg = fmin(mg, dqx - (double)(cx-1)*h);
  if (cx+1 < GRES-1) mg = fmin(mg, (double)(cx+2)*h - dqx);
  if (cy-1 > 0)      mg = fmin(mg, dqy - (double)(cy-1)*h);
  if (cy+1 < GRES-1) mg = fmin(mg, (double)(cy+2)*h - dqy);
  if (cz-1 > 0)      mg = fmin(mg, dqz - (double)(cz-1)*h);
  if (cz+1 < GRES-1) mg = fmin(mg, (double)(cz+2)*h - dqz);
  bool ok = (mg*mg > (double)b16 + 1.0e-5);
  if (lane == 0) flags[t] = ok ? 0 : 1;
}

// Exact serial fallback for flagged points; writes neighbor slots.
__global__ __launch_bounds__(256) void knn_fallback(const float4* __restrict__ pos4, const int* __restrict__ pidx,
                                                    const int* __restrict__ starts, const int* __restrict__ cnt,
                                                    const int* __restrict__ inv,
                                                    const char* __restrict__ flags, int* __restrict__ ind_slot){
  int t = blockIdx.x*256 + threadIdx.x;
  if (t >= N_PTS || !flags[t]) return;
  float4 qp = pos4[t];
  float qx = qp.x, qy = qp.y, qz = qp.z, qsq = qp.w;
  int cx = min(GRES-1, max(0,(int)(qx*(float)GRES)));
  int cy = min(GRES-1, max(0,(int)(qy*(float)GRES)));
  int cz = min(GRES-1, max(0,(int)(qz*(float)GRES)));
  float bd[KNB]; int bi[KNB];
  #pragma unroll
  for (int k=0;k<KNB;++k){ bd[k] = 3.0e38f; bi[k] = 0x7fffffff; }
  const double cinv = 0.125;
  for (int r = 0; r < GRES; ++r){
    int zlo = max(0, cz-r), zhi = min(GRES-1, cz+r);
    int ylo = max(0, cy-r), yhi = min(GRES-1, cy+r);
    int xlo = max(0, cx-r), xhi = min(GRES-1, cx+r);
    for (int zz = zlo; zz <= zhi; ++zz){
      for (int yy = ylo; yy <= yhi; ++yy){
        for (int xx = xlo; xx <= xhi; ++xx){
          int ring = max(abs(zz-cz), max(abs(yy-cy), abs(xx-cx)));
          if (ring != r) continue;
          int c = (zz*GRES+yy)*GRES+xx;
          int s0 = starts[c], e = s0 + cnt[c];
          for (int s = s0; s < e; ++s){
            float4 pc = pos4[s];
            int idx = pidx[s];
            float dot = __fmaf_rn(qz, pc.z, __fmaf_rn(qy, pc.y, __fmul_rn(qx, pc.x)));
            float d   = __fsub_rn(__fadd_rn(qsq, pc.w), __fmul_rn(2.0f, dot));
            bool adm = (d < bd[KNB-1]) || (d == bd[KNB-1] && idx < bi[KNB-1]);
            if (adm){
              #pragma unroll
              for (int p = KNB-1; p >= 1; --p){
                float pd = bd[p-1]; int pi = bi[p-1];
                bool sh  = (pd > d) || (pd == d && pi > idx);
                bool ins = (!sh) && ((bd[p] > d) || (bd[p] == d && bi[p] > idx));
                bd[p] = sh ? pd : (ins ? d   : bd[p]);
                bi[p] = sh ? pi : (ins ? idx : bi[p]);
              }
              bool s0b = (bd[0] > d) || (bd[0] == d && bi[0] > idx);
              if (s0b){ bd[0] = d; bi[0] = idx; }
            }
          }
        }
      }
    }
    if (bd[KNB-1] < 3.0e37f){
      double mg = 1.0e300;
      double dqx=(double)qx, dqy=(double)qy, dqz=(double)qz;
      if (cx - r > 0)      mg = fmin(mg, dqx - (double)(cx-r)*cinv);
      if (cx + r < GRES-1) mg = fmin(mg, (double)(cx+r+1)*cinv - dqx);
      if (cy - r > 0)      mg = fmin(mg, dqy - (double)(cy-r)*cinv);
      if (cy + r < GRES-1) mg = fmin(mg, (double)(cy+r+1)*cinv - dqy);
      if (cz - r > 0)      mg = fmin(mg, dqz - (double)(cz-r)*cinv);
      if (cz + r < GRES-1) mg = fmin(mg, (double)(cz+r+1)*cinv - dqz);
      if (mg*mg > (double)bd[KNB-1] + 1.0e-5) break;
    }
  }
  #pragma unroll
  for (int k=0;k<KNB;++k) ind_slot[t*KNB + k] = inv[bi[k]];
}

// ---------------- weight packing into B-fragment order (7 weights, one launch) ----------------
__global__ __launch_bounds__(256) void pack_all(const float* __restrict__ w0, const float* __restrict__ w1,
                                                const float* __restrict__ w2, const float* __restrict__ w3,
                                                const float* __restrict__ w4, const float* __restrict__ w5,
                                                const float* __restrict__ w6,
                                                short* __restrict__ dst){
  int slot = blockIdx.y;
  const float* src = (slot==0)?w0:(slot==1)?w1:(slot==2)?w2:(slot==3)?w3:(slot==4)?w4:(slot==5)?w5:w6;
  int f = blockIdx.x*256 + threadIdx.x;
  int j  = f & 7;
  int ln = (f >> 3) & 63;
  int ks = (f >> 9) & 3;
  int nt = f >> 11;
  int k = ks*32 + ((ln >> 4) << 3) + j;
  int n = nt*16 + (ln & 15);
  dst[slot*16384 + f] = (short)f2b(src[k*DIMF + n]);
}

// ---------------- proj: q/xk/xv = x@W (bf16 outputs, SLOT order) ----------------
__global__ __launch_bounds__(256) void proj_kernel(const float* __restrict__ x, const int* __restrict__ pidx,
                                                   const short* __restrict__ pw,
                                                   unsigned short* __restrict__ q, unsigned short* __restrict__ xk,
                                                   unsigned short* __restrict__ xv){
  __shared__ __align__(16) char Abuf[32768];
  int tid = threadIdx.x, lane = tid & 63, wv = tid >> 6;
  int r0 = blockIdx.x * 128;
  {
    int row = tid >> 1, half = tid & 1;
    int orig = pidx[r0 + row];
    const float4* xr = (const float4*)(x + (size_t)orig*DIMF + half*64);
    #pragma unroll
    for (int i=0;i<8;++i){
      float4 a = xr[2*i], b = xr[2*i+1];
      bf16x8 v;
      v[0]=(short)f2b(a.x); v[1]=(short)f2b(a.y); v[2]=(short)f2b(a.z); v[3]=(short)f2b(a.w);
      v[4]=(short)f2b(b.x); v[5]=(short)f2b(b.y); v[6]=(short)f2b(b.z); v[7]=(short)f2b(b.w);
      *(bf16x8*)(&Abuf[row*256 + ((half*128 + i*16) ^ ((row&7)<<4))]) = v;
    }
  }
  __syncthreads();
  #pragma unroll 1
  for (int w = 0; w < 3; ++w){
    const bf16x8* bw = (const bf16x8*)(pw + w*16384);
    unsigned short* dst = (w==0) ? q : (w==1) ? xk : xv;
    f32x4 acc[2][8];
    #pragma unroll
    for (int i=0;i<2;++i)
      #pragma unroll
      for (int nt=0;nt<8;++nt) acc[i][nt] = (f32x4){0.f,0.f,0.f,0.f};
    #pragma unroll
    for (int ks=0;ks<4;++ks){
      int ra = (wv*2)*16 + (lane&15);
      int rb = (wv*2+1)*16 + (lane&15);
      int cb = ks*64 + ((lane>>4)<<4);
      bf16x8 a0 = *(const bf16x8*)(&Abuf[ra*256 + (cb ^ ((ra&7)<<4))]);
      bf16x8 a1 = *(const bf16x8*)(&Abuf[rb*256 + (cb ^ ((rb&7)<<4))]);
      #pragma unroll
      for (int nt=0;nt<8;++nt){
        bf16x8 b = bw[(nt*4+ks)*64 + lane];
        acc[0][nt] = __builtin_amdgcn_mfma_f32_16x16x32_bf16(a0, b, acc[0][nt], 0, 0, 0);
        acc[1][nt] = __builtin_amdgcn_mfma_f32_16x16x32_bf16(a1, b, acc[1][nt], 0, 0, 0);
      }
    }
    #pragma unroll
    for (int i=0;i<2;++i){
      int mt = wv*2+i;
      #pragma unroll
      for (int nt=0;nt<8;++nt){
        #pragma unroll
        for (int r=0;r<4;++r){
          int grow = r0 + mt*16 + ((lane>>4)<<2) + r;
          dst[(size_t)grow*DIMF + nt*16 + (lane&15)] = f2b(acc[i][nt][r]);
        }
      }
    }
  }
}

// ---------------- fused main kernel: 8 sorted slots / wg, 8 waves, 1 m-tile/wave ----------------
__global__ __launch_bounds__(512, 2) void main_kernel(
    const float* __restrict__ x, const float4* __restrict__ pos4, const int* __restrict__ pidx,
    const float* __restrict__ pe_w1, const float* __restrict__ pe_b1, const float* __restrict__ pe_b2,
    const float* __restrict__ mid_b1, const float* __restrict__ mid_b2, const float* __restrict__ fin_b,
    const unsigned short* __restrict__ qarr, const unsigned short* __restrict__ xkarr,
    const unsigned short* __restrict__ xvarr,
    const int* __restrict__ ind_slot, const short* __restrict__ pw,
    float* __restrict__ out)
{
  __shared__ __align__(16) char peLDS[32768];
  __shared__ float aggT[DIMF][8];     // transposed agg: [col][point]
  __shared__ int indbuf[128];
  __shared__ int origbuf[8];
  int tid = threadIdx.x;
  int lane = tid & 63;
  int wv = tid >> 6;                  // 0..7, owns m-tile mt = wv
  int t0 = blockIdx.x * 8;
  if (tid < 128) indbuf[tid] = ind_slot[blockIdx.x*128 + tid];
  if (tid < 8) origbuf[tid] = pidx[t0 + tid];
  __syncthreads();

  int g = lane >> 4, kl = lane & 15;
  int mt = wv;

  // ---- early-issue z gathers (latency hides under tfrag build + GEMM1) ----
  int nb4[4];
  #pragma unroll
  for (int r=0;r<4;++r) nb4[r] = indbuf[mt*16 + g*4 + r];
  unsigned short zraw[8][4];
  #pragma unroll
  for (int nt=0;nt<8;++nt)
    #pragma unroll
    for (int r=0;r<4;++r)
      zraw[nt][r] = xvarr[(size_t)nb4[r]*DIMF + nt*16 + kl];

  // ---- Phase A: t = relu(rel @ pe_w1 + pe_b1) directly as A-fragments ----
  int nbr = indbuf[mt*16 + kl];
  bf16x8 tfrag[4];
  {
    float4 pq = pos4[t0+mt];
    float4 pn = pos4[nbr];
    float rx = pq.x-pn.x, ry = pq.y-pn.y, rz = pq.z-pn.z;
    #pragma unroll
    for (int ks=0;ks<4;++ks){
      int c0 = ks*32 + g*8;
      const float4* w0 = (const float4*)(pe_w1 + c0);
      const float4* w1 = (const float4*)(pe_w1 + DIMF + c0);
      const float4* w2 = (const float4*)(pe_w1 + 2*DIMF + c0);
      const float4* bb = (const float4*)(pe_b1 + c0);
      float4 wa0=w0[0], wa1=w0[1], wb0=w1[0], wb1=w1[1], wc0=w2[0], wc1=w2[1], wd0=bb[0], wd1=bb[1];
      float wa[8]={wa0.x,wa0.y,wa0.z,wa0.w,wa1.x,wa1.y,wa1.z,wa1.w};
      float wb[8]={wb0.x,wb0.y,wb0.z,wb0.w,wb1.x,wb1.y,wb1.z,wb1.w};
      float wc[8]={wc0.x,wc0.y,wc0.z,wc0.w,wc1.x,wc1.y,wc1.z,wc1.w};
      float wd[8]={wd0.x,wd0.y,wd0.z,wd0.w,wd1.x,wd1.y,wd1.z,wd1.w};
      bf16x8 v;
      #pragma unroll
      for (int j=0;j<8;++j){
        float tv = fmaf(rx, wa[j], fmaf(ry, wb[j], fmaf(rz, wc[j], wd[j])));
        v[j] = (short)f2b(fmaxf(tv, 0.f));
      }
      tfrag[ks] = v;
    }
  }

  f32x4 acc[8];

  // ---- GEMM1: pe = t @ pe_w2 + pe_b2 ----
  {
    const bf16x8* bw = (const bf16x8*)(pw + 3*16384);
    #pragma unroll
    for (int nt=0;nt<8;++nt){
      float bv = pe_b2[nt*16 + kl];
      acc[nt] = (f32x4){bv,bv,bv,bv};
    }
    #pragma unroll
    for (int ks=0;ks<4;++ks){
      #pragma unroll
      for (int nt=0;nt<8;++nt){
        bf16x8 b = bw[(nt*4+ks)*64 + lane];
        acc[nt] = __builtin_amdgcn_mfma_f32_16x16x32_bf16(tfrag[ks], b, acc[nt], 0, 0, 0);
      }
    }
  }

  // ---- Epilogue 1: pe -> LDS (bf16, swizzled); z = xv + pe -> bf16 regs ----
  bf16x4 zb[8];
  #pragma unroll
  for (int nt=0;nt<8;++nt){
    int col = nt*16 + kl;
    bf16x4 zv;
    #pragma unroll
    for (int r=0;r<4;++r){
      int row = mt*16 + g*4 + r;
      float pe = acc[nt][r];
      *(unsigned short*)&peLDS[row*256 + ((col*2) ^ ((row&7)<<4))] = f2b(pe);
      zv[r] = (short)f2b(b2f(zraw[nt][r]) + pe);
    }
    zb[nt] = zv;
  }

  // prefetch q/k A-layout vector gathers (fly across the barrier drain)
  bf16x8 q8[4], k8[4];
  {
    const unsigned short* qrow = qarr + (size_t)(t0+mt)*DIMF;
    const unsigned short* krow = xkarr + (size_t)nbr*DIMF;
    #pragma unroll
    for (int ks=0;ks<4;++ks){
      int c0 = ks*32 + g*8;
      q8[ks] = *(const bf16x8*)(qrow + c0);
      k8[ks] = *(const bf16x8*)(krow + c0);
    }
  }
  __syncthreads();

  // ---- GEMM2 A-build: h = (q - xk) + pe ----
  bf16x8 hfrag[4];
  {
    int row = mt*16 + kl;
    #pragma unroll
    for (int ks=0;ks<4;++ks){
      int c0 = ks*32 + g*8;
      bf16x8 p8 = *(const bf16x8*)(&peLDS[row*256 + ((c0*2) ^ ((row&7)<<4))]);
      bf16x8 v;
      #pragma unroll
      for (int j=0;j<8;++j){
        float hf = (b2fs(q8[ks][j]) - b2fs(k8[ks][j])) + b2fs(p8[j]);
        v[j] = (short)f2b(hf);
      }
      hfrag[ks] = v;
    }
  }

  // ---- GEMM2: u = relu(h @ mid_w1 + mid_b1) ----
  {
    const bf16x8* bw = (const bf16x8*)(pw + 4*16384);
    #pragma unroll
    for (int nt=0;nt<8;++nt){
      float bv = mid_b1[nt*16 + kl];
      acc[nt] = (f32x4){bv,bv,bv,bv};
    }
    #pragma unroll
    for (int ks=0;ks<4;++ks){
      #pragma unroll
      for (int nt=0;nt<8;++nt){
        bf16x8 b = bw[(nt*4+ks)*64 + lane];
        acc[nt] = __builtin_amdgcn_mfma_f32_16x16x32_bf16(hfrag[ks], b, acc[nt], 0, 0, 0);
      }
    }
  }
  __syncthreads();   // all pe reads done -> safe to overwrite with u
  #pragma unroll
  for (int nt=0;nt<8;++nt){
    int col = nt*16 + kl;
    #pragma unroll
    for (int r=0;r<4;++r){
      int row = mt*16 + g*4 + r;
      *(unsigned short*)&peLDS[row*256 + ((col*2) ^ ((row&7)<<4))] = f2b(fmaxf(acc[nt][r], 0.f));
    }
  }
  __syncthreads();

  // ---- GEMM3: y = u @ mid_w2 + mid_b2 ; softmax over K; agg -> aggT ----
  {
    const bf16x8* bw = (const bf16x8*)(pw + 5*16384);
    #pragma unroll
    for (int nt=0;nt<8;++nt){
      float bv = mid_b2[nt*16 + kl];
      acc[nt] = (f32x4){bv,bv,bv,bv};
    }
    #pragma unroll
    for (int ks=0;ks<4;++ks){
      int ra = mt*16 + kl;
      int cb = ks*64 + g*16;
      bf16x8 a0 = *(const bf16x8*)(&peLDS[ra*256 + (cb ^ ((ra&7)<<4))]);
      #pragma unroll
      for (int nt=0;nt<8;++nt){
        bf16x8 b = bw[(nt*4+ks)*64 + lane];
        acc[nt] = __builtin_amdgcn_mfma_f32_16x16x32_bf16(a0, b, acc[nt], 0, 0, 0);
      }
    }
    const float invS = 0.08838834764831843f;   // 1/sqrt(128)
    #pragma unroll
    for (int nt=0;nt<8;++nt){
      f32x4 y = acc[nt];
      float mx = fmaxf(fmaxf(y[0],y[1]), fmaxf(y[2],y[3]));
      mx = fmaxf(mx, __shfl_xor(mx, 16, 64));
      mx = fmaxf(mx, __shfl_xor(mx, 32, 64));
      float e0 = __expf((y[0]-mx)*invS);
      float e1 = __expf((y[1]-mx)*invS);
      float e2 = __expf((y[2]-mx)*invS);
      float e3 = __expf((y[3]-mx)*invS);
      float ssum = e0+e1+e2+e3;
      ssum += __shfl_xor(ssum, 16, 64);
      ssum += __shfl_xor(ssum, 32, 64);
      bf16x4 zv = zb[nt];
      float ps = (e0*b2fs(zv[0]) + e1*b2fs(zv[1]) + e2*b2fs(zv[2]) + e3*b2fs(zv[3])) / ssum;
      ps += __shfl_xor(ps, 16, 64);
      ps += __shfl_xor(ps, 32, 64);
      if (lane < 16) aggT[nt*16 + lane][mt] = ps;
    }
  }
  __syncthreads();

  // ---- Final via MFMA: out = agg @ fin_w + fin_b + x ; wave wv owns N-tile nt=wv ----
  {
    const bf16x8* bwf = (const bf16x8*)(pw + 6*16384);
    f32x4 facc = (f32x4){0.f,0.f,0.f,0.f};
    #pragma unroll
    for (int ks=0;ks<4;++ks){
      int c0 = ks*32 + g*8;
      bf16x8 a;
      #pragma unroll
      for (int j=0;j<8;++j)
        a[j] = (kl < 8) ? (short)f2b(aggT[c0+j][kl]) : (short)0;
      bf16x8 b = bwf[(wv*4+ks)*64 + lane];
      facc = __builtin_amdgcn_mfma_f32_16x16x32_bf16(a, b, facc, 0, 0, 0);
    }
    int col = wv*16 + kl;
    float fb = fin_b[col];
    if (g < 2){
      #pragma unroll
      for (int r=0;r<4;++r){
        int prow = g*4 + r;
        int o = origbuf[prow];
        out[(size_t)o*DIMF + col] = facc[r] + fb + x[(size_t)o*DIMF + col];
      }
    }
  }
}

extern "C" void kernel_launch(void* const* d_in, const int* in_sizes, int n_in,
                              void* d_out, int out_size, void* d_ws, size_t ws_size,
                              hipStream_t stream)
{
  (void)in_sizes; (void)n_in; (void)out_size; (void)ws_size;
  const float* x      = (const float*)d_in[0];
  const float* pos    = (const float*)d_in[1];
  const float* Wq     = (const float*)d_in[2];
  const float* Wk     = (const float*)d_in[3];
  const float* Wv     = (const float*)d_in[4];
  const float* mid_w1 = (const float*)d_in[5];
  const float* mid_b1 = (const float*)d_in[6];
  const float* mid_w2 = (const float*)d_in[7];
  const float* mid_b2 = (const float*)d_in[8];
  const float* pe_w1  = (const float*)d_in[9];
  const float* pe_b1  = (const float*)d_in[10];
  const float* pe_w2  = (const float*)d_in[11];
  const float* pe_b2  = (const float*)d_in[12];
  const float* fin_w  = (const float*)d_in[13];
  const float* fin_b  = (const float*)d_in[14];
  float* out = (float*)d_out;
  char* ws = (char*)d_ws;

  int*    cellcnt = (int*)   (ws + 0);         //  2 KB
  int*    fillp   = (int*)   (ws + 4096);      //  2 KB
  int*    starts  = (int*)   (ws + 8192);      //  2 KB
  char*   flags   = (char*)  (ws + 18432);     // 16 KB
  int*    pidx    = (int*)   (ws + 49152);     // 64 KB
  float4* pos4    = (float4*)(ws + 114688);    // 256 KB
  int*    ind     = (int*)   (ws + 376832);    //  1 MB (neighbor slots)
  short*  pw      = (short*) (ws + 1425408);   // 224 KB (7 packed 128x128 bf16 weights)
  int*    inv     = (int*)   (ws + 1654784);   // 64 KB
  unsigned short* qarr  = (unsigned short*)(ws + 1720320);   // 4 MB
  unsigned short* xkarr = (unsigned short*)(ws + 5914624);   // 4 MB
  unsigned short* xvarr = (unsigned short*)(ws + 10108928);  // 4 MB (end ~14.3 MB)

  hipMemsetAsync(cellcnt, 0, NCELL*sizeof(int), stream);
  count_kernel  <<<N_PTS/256, 256, 0, stream>>>(pos, cellcnt);
  scan_kernel   <<<1,         256, 0, stream>>>(cellcnt, starts, fillp);
  scatter_kernel<<<N_PTS/256, 256, 0, stream>>>(pos, fillp, pos4, pidx, inv);
  knn_query64   <<<N_PTS/4,   256, 0, stream>>>(pos4, pidx, starts, cellcnt, inv, ind, flags);
  knn_fallback  <<<N_PTS/256, 256, 0, stream>>>(pos4, pidx, starts, cellcnt, inv, flags, ind);

  pack_all<<<dim3(64,7), 256, 0, stream>>>(Wq, Wk, Wv, pe_w2, mid_w1, mid_w2, fin_w, pw);

  proj_kernel<<<N_PTS/128, 256, 0, stream>>>(x, pidx, pw, qarr, xkarr, xvarr);

  main_kernel<<<N_PTS/8, 512, 0, stream>>>(x, pos4, pidx, pe_w1, pe_b1, pe_b2, mid_b1, mid_b2, fin_b,
                                           qarr, xkarr, xvarr, ind, pw, out);
}